// Round 1
// baseline (1617.292 us; speedup 1.0000x reference)
//
#include <hip/hip_runtime.h>
#include <hip/hip_bf16.h>

static constexpr int S_    = 2048;
static constexpr int D_    = 2048;
static constexpr int NH_   = 32;
static constexpr int NKVH_ = 8;
static constexpr int HD_   = 64;
static constexpr int KVD_  = NKVH_ * HD_;   // 512

using bf16 = __hip_bfloat16;
typedef __attribute__((ext_vector_type(4))) float f32x4;
typedef __attribute__((ext_vector_type(8))) short s16x8;

__device__ inline unsigned short f2bf_bits(float f) {
  bf16 h = __float2bfloat16(f);
  union { bf16 b; unsigned short u; } cv; cv.b = h; return cv.u;
}

// ---------- generic f32 -> bf16 cast, n divisible by 4 ----------
__global__ __launch_bounds__(256) void cast4_kernel(const float* __restrict__ in,
                                                    bf16* __restrict__ out, int n4) {
  int i = blockIdx.x * 256 + threadIdx.x;
  if (i >= n4) return;
  float4 v = reinterpret_cast<const float4*>(in)[i];
  ushort4 o;
  o.x = f2bf_bits(v.x); o.y = f2bf_bits(v.y); o.z = f2bf_bits(v.z); o.w = f2bf_bits(v.w);
  reinterpret_cast<ushort4*>(out)[i] = o;
}

// ---------- bf16 MFMA GEMM: C[M][N] = X[M][K] @ W[N][K]^T (m97 structure) ----------
__device__ inline void gld_lds16(const void* g, void* l) {
  __builtin_amdgcn_global_load_lds((const __attribute__((address_space(1))) void*)g,
                                   (__attribute__((address_space(3))) void*)l, 16, 0, 0);
}

__global__ __launch_bounds__(256) void gemm_bt_kernel(
    const bf16* __restrict__ X, const bf16* __restrict__ W,
    float* __restrict__ C, int M, int N, int K)
{
  __shared__ __align__(16) bf16 As[128 * 32];
  __shared__ __align__(16) bf16 Bs[128 * 32];
  const int tid = threadIdx.x;
  const int lane = tid & 63;
  const int wid = tid >> 6;
  const int m0 = blockIdx.y * 128;
  const int n0 = blockIdx.x * 128;
  const int wm = (wid >> 1) * 64;
  const int wn = (wid & 1) * 64;

  f32x4 acc[4][4] = {};
  const int kg = (lane >> 4) * 8;   // k element offset inside fragment
  const int fr = lane & 15;         // row/col index inside 16-tile

  for (int kt = 0; kt < K; kt += 32) {
    #pragma unroll
    for (int c = 0; c < 2; ++c) {
      int o  = c * 4096 + tid * 16;    // byte offset within 8KB tile
      int r  = o >> 6;                 // tile row (64B per row)
      int ke = (o & 63) >> 1;          // k element within row
      const bf16* srcA = X + (size_t)(m0 + r) * K + kt + ke;
      gld_lds16(srcA, (char*)As + o);
      int wr = n0 + r; if (wr > N - 1) wr = N - 1;   // clamp for N<128 tiles
      const bf16* srcB = W + (size_t)wr * K + kt + ke;
      gld_lds16(srcB, (char*)Bs + o);
    }
    __syncthreads();
    s16x8 af[4], bfr[4];
    #pragma unroll
    for (int i = 0; i < 4; ++i) {
      af[i]  = *reinterpret_cast<const s16x8*>(&As[(wm + i * 16 + fr) * 32 + kg]);
      bfr[i] = *reinterpret_cast<const s16x8*>(&Bs[(wn + i * 16 + fr) * 32 + kg]);
    }
    #pragma unroll
    for (int i = 0; i < 4; ++i)
      #pragma unroll
      for (int j = 0; j < 4; ++j)
        acc[i][j] = __builtin_amdgcn_mfma_f32_16x16x32_bf16(af[i], bfr[j], acc[i][j], 0, 0, 0);
    __syncthreads();
  }

  const int cr = (lane >> 4) * 4;
  const int cc = lane & 15;
  #pragma unroll
  for (int i = 0; i < 4; ++i)
    #pragma unroll
    for (int j = 0; j < 4; ++j) {
      int gn = n0 + wn + j * 16 + cc;
      if (gn >= N) continue;
      #pragma unroll
      for (int r = 0; r < 4; ++r) {
        int gm = m0 + wm + i * 16 + cr + r;
        C[(size_t)gm * N + gn] = acc[i][j][r];
      }
    }
}

// ---------- router softmax: rw[s][8] = softmax(x[s] @ Rt^T) ----------
__device__ inline float tofloat(float v) { return v; }
__device__ inline float tofloat(bf16 v) { return __bfloat162float(v); }

template <typename T>
__global__ __launch_bounds__(256) void router_rw_kernel(const T* __restrict__ X,
    const float* __restrict__ Rt, float* __restrict__ rw) {
  int s = blockIdx.x, t = threadIdx.x;
  float part[8] = {};
  for (int d = t; d < D_; d += 256) {
    float xv = tofloat(X[(size_t)s * D_ + d]);
    #pragma unroll
    for (int e = 0; e < 8; ++e) part[e] += xv * Rt[e * D_ + d];
  }
  #pragma unroll
  for (int e = 0; e < 8; ++e)
    for (int off = 32; off; off >>= 1) part[e] += __shfl_xor(part[e], off);
  __shared__ float red[4][8];
  int w = t >> 6, lane = t & 63;
  if (lane == 0) {
    #pragma unroll
    for (int e = 0; e < 8; ++e) red[w][e] = part[e];
  }
  __syncthreads();
  if (t == 0) {
    float lg[8], mx = -1e30f;
    #pragma unroll
    for (int e = 0; e < 8; ++e) { lg[e] = red[0][e] + red[1][e] + red[2][e] + red[3][e]; mx = fmaxf(mx, lg[e]); }
    float sum = 0.f;
    #pragma unroll
    for (int e = 0; e < 8; ++e) { lg[e] = __expf(lg[e] - mx); sum += lg[e]; }
    float inv = 1.f / sum;
    #pragma unroll
    for (int e = 0; e < 8; ++e) rw[s * 8 + e] = lg[e] * inv;
  }
}

// ---------- Out[s][o] += SCALING * sum_{e,r} rw[s][e]*H[s][e*8+r]*Bw[e][o][r] ----------
__global__ __launch_bounds__(256) void lora_add_kernel(float* __restrict__ Out,
    const float* __restrict__ H, const float* __restrict__ rw,
    const float* __restrict__ Bw, int OUT) {
  int s = blockIdx.x, t = threadIdx.x;
  __shared__ float g[64];
  if (t < 64) g[t] = 4.0f * rw[s * 8 + (t >> 3)] * H[(size_t)s * 64 + t];
  __syncthreads();
  for (int o = t; o < OUT; o += 256) {
    float acc = 0.f;
    #pragma unroll
    for (int er = 0; er < 64; ++er)
      acc += g[er] * Bw[((size_t)(er >> 3) * OUT + o) * 8 + (er & 7)];
    Out[(size_t)s * OUT + o] += acc;
  }
}

// ---------- RoPE ----------
__global__ __launch_bounds__(256) void rope_q_kernel(const float* __restrict__ Qf,
    const float* __restrict__ fc, const float* __restrict__ fs, bf16* __restrict__ Qb) {
  int idx = blockIdx.x * 256 + threadIdx.x;   // S*NH*32
  int i = idx & 31, h = (idx >> 5) & 31, s = idx >> 10;
  float c = fc[s * 32 + i], sn = fs[s * 32 + i];
  size_t base = (size_t)s * 2048 + h * 64 + 2 * i;
  float xr = Qf[base], xi = Qf[base + 1];
  Qb[base]     = __float2bfloat16(xr * c - xi * sn);
  Qb[base + 1] = __float2bfloat16(xr * sn + xi * c);
}

__global__ __launch_bounds__(256) void rope_kt_kernel(const float* __restrict__ Kf,
    const float* __restrict__ fc, const float* __restrict__ fs, bf16* __restrict__ Kt) {
  int idx = blockIdx.x * 256 + threadIdx.x;   // NKVH*32*S, s fastest
  int s = idx & 2047;
  int rest = idx >> 11;
  int i = rest & 31, hk = rest >> 5;
  float c = fc[s * 32 + i], sn = fs[s * 32 + i];
  size_t src = (size_t)s * KVD_ + hk * 64 + 2 * i;
  float xr = Kf[src], xi = Kf[src + 1];
  Kt[(size_t)(hk * 64 + 2 * i) * S_ + s]     = __float2bfloat16(xr * c - xi * sn);
  Kt[(size_t)(hk * 64 + 2 * i + 1) * S_ + s] = __float2bfloat16(xr * sn + xi * c);
}

// ---------- flash attention: 1 wave per (q row, head), online softmax ----------
__global__ __launch_bounds__(64) void flash_attn_kernel(const bf16* __restrict__ Qb,
    const bf16* __restrict__ Kt, const bf16* __restrict__ Vb, bf16* __restrict__ Ob) {
  int q = blockIdx.x, h = blockIdx.y, hk = h >> 2;
  int lane = threadIdx.x;
  __shared__ float q_lds[64];
  __shared__ float p_lds[64];
  q_lds[lane] = __bfloat162float(Qb[(size_t)q * 2048 + h * 64 + lane]) * 0.125f;
  __syncthreads();
  float m = -1e30f, l = 0.f, o = 0.f;
  const bf16* Kh = Kt + (size_t)hk * 64 * S_;
  const bf16* Vh = Vb + hk * 64;
  int ntiles = (q >> 6) + 1;
  for (int t = 0; t < ntiles; ++t) {
    int j0 = t << 6;
    int j = j0 + lane;
    float sc = 0.f;
    #pragma unroll 8
    for (int d = 0; d < 64; ++d)
      sc += q_lds[d] * __bfloat162float(Kh[(size_t)d * S_ + j]);
    if (j > q) sc = -1e30f;
    float tm = sc;
    for (int off = 32; off; off >>= 1) tm = fmaxf(tm, __shfl_xor(tm, off));
    float newm = fmaxf(m, tm);
    float rescale = __expf(m - newm);
    o *= rescale; l *= rescale;
    float p = __expf(sc - newm);
    l += p; m = newm;
    __syncthreads();
    p_lds[lane] = p;
    __syncthreads();
    #pragma unroll 8
    for (int j2 = 0; j2 < 64; ++j2)
      o += p_lds[j2] * __bfloat162float(Vh[(size_t)(j0 + j2) * KVD_ + lane]);
  }
  for (int off = 32; off; off >>= 1) l += __shfl_xor(l, off);
  Ob[(size_t)q * 2048 + h * 64 + lane] = __float2bfloat16(o / l);
}

extern "C" void kernel_launch(void* const* d_in, const int* in_sizes, int n_in,
                              void* d_out, int out_size, void* d_ws, size_t ws_size,
                              hipStream_t stream) {
  const float* x   = (const float*)d_in[0];
  const float* fc  = (const float*)d_in[3];
  const float* fs  = (const float*)d_in[4];
  const float* wq  = (const float*)d_in[5];
  const float* wk  = (const float*)d_in[6];
  const float* wv  = (const float*)d_in[7];
  const float* wo  = (const float*)d_in[8];
  const float* lqR = (const float*)d_in[9];
  const float* lqA = (const float*)d_in[10];
  const float* lqB = (const float*)d_in[11];
  const float* lkR = (const float*)d_in[12];
  const float* lkA = (const float*)d_in[13];
  const float* lkB = (const float*)d_in[14];
  const float* lvR = (const float*)d_in[15];
  const float* lvA = (const float*)d_in[16];
  const float* lvB = (const float*)d_in[17];
  const float* loR = (const float*)d_in[18];
  const float* loA = (const float*)d_in[19];
  const float* loB = (const float*)d_in[20];
  float* out = (float*)d_out;
  char* ws = (char*)d_ws;

  if (ws_size < 58000000u) return;  // workspace too small: bail cleanly

  bf16* xb   = (bf16*)(ws + 0);            // 8MB ; aliased as AOb later
  bf16* wqb  = (bf16*)(ws + 8388608);      // 8MB ; aliased as Qb later
  bf16* wkb  = (bf16*)(ws + 16777216);     // 2MB ; aliased as Ktb later
  bf16* wvb  = (bf16*)(ws + 18874368);     // 2MB ; aliased as Vb later
  bf16* wob  = (bf16*)(ws + 20971520);     // 8MB
  bf16* lqAb = (bf16*)(ws + 29360128);     // 256KB
  bf16* lkAb = (bf16*)(ws + 29622272);
  bf16* lvAb = (bf16*)(ws + 29884416);
  bf16* loAb = (bf16*)(ws + 30146560);
  float* Qf  = (float*)(ws + 30408704);    // 16MB
  float* Kf  = (float*)(ws + 47185920);    // 4MB
  float* Vf  = (float*)(ws + 51380224);    // 4MB
  float* Hq  = (float*)(ws + 55574528);    // 512KB
  float* Hk  = (float*)(ws + 56098816);
  float* Hv  = (float*)(ws + 56623104);
  float* Ho  = (float*)(ws + 57147392);
  float* rwq = (float*)(ws + 57671680);    // 64KB each
  float* rwk = (float*)(ws + 57737216);
  float* rwv = (float*)(ws + 57802752);
  float* rwo = (float*)(ws + 57868288);

  bf16* AOb = xb;
  bf16* Qb  = wqb;
  bf16* Ktb = wkb;
  bf16* Vb  = wvb;

  auto cast = [&](const float* src, bf16* dst, int n) {
    cast4_kernel<<<dim3((n / 4 + 255) / 256), dim3(256), 0, stream>>>(src, dst, n / 4);
  };
  cast(x,  xb,  S_ * D_);
  cast(wq, wqb, D_ * D_);
  cast(wk, wkb, KVD_ * D_);
  cast(wv, wvb, KVD_ * D_);
  cast(wo, wob, D_ * D_);
  cast(lqA, lqAb, 64 * D_);
  cast(lkA, lkAb, 64 * D_);
  cast(lvA, lvAb, 64 * D_);
  cast(loA, loAb, 64 * D_);

  auto gemm = [&](const bf16* X_, const bf16* W_, float* C_, int M, int N, int K) {
    gemm_bt_kernel<<<dim3((N + 127) / 128, M / 128), dim3(256), 0, stream>>>(X_, W_, C_, M, N, K);
  };
  gemm(xb, wqb,  Qf, S_, D_,   D_);
  gemm(xb, wkb,  Kf, S_, KVD_, D_);
  gemm(xb, wvb,  Vf, S_, KVD_, D_);
  gemm(xb, lqAb, Hq, S_, 64,   D_);
  gemm(xb, lkAb, Hk, S_, 64,   D_);
  gemm(xb, lvAb, Hv, S_, 64,   D_);

  router_rw_kernel<float><<<dim3(S_), dim3(256), 0, stream>>>(x, lqR, rwq);
  router_rw_kernel<float><<<dim3(S_), dim3(256), 0, stream>>>(x, lkR, rwk);
  router_rw_kernel<float><<<dim3(S_), dim3(256), 0, stream>>>(x, lvR, rwv);

  lora_add_kernel<<<dim3(S_), dim3(256), 0, stream>>>(Qf, Hq, rwq, lqB, D_);
  lora_add_kernel<<<dim3(S_), dim3(256), 0, stream>>>(Kf, Hk, rwk, lkB, KVD_);
  lora_add_kernel<<<dim3(S_), dim3(256), 0, stream>>>(Vf, Hv, rwv, lvB, KVD_);

  rope_q_kernel<<<dim3(S_ * NH_ * 32 / 256),  dim3(256), 0, stream>>>(Qf, fc, fs, Qb);
  rope_kt_kernel<<<dim3(S_ * NKVH_ * 32 / 256), dim3(256), 0, stream>>>(Kf, fc, fs, Ktb);
  cast(Vf, Vb, S_ * KVD_);

  flash_attn_kernel<<<dim3(S_, NH_), dim3(64), 0, stream>>>(Qb, Ktb, Vb, AOb);

  router_rw_kernel<bf16><<<dim3(S_), dim3(256), 0, stream>>>(AOb, loR, rwo);
  gemm(AOb, loAb, Ho, S_, 64, D_);
  gemm(AOb, wob,  out, S_, D_, D_);
  lora_add_kernel<<<dim3(S_), dim3(256), 0, stream>>>(out, Ho, rwo, loB, D_);
}

// Round 2
// 674.751 us; speedup vs baseline: 2.3969x; 2.3969x over previous
//
#include <hip/hip_runtime.h>
#include <hip/hip_bf16.h>

static constexpr int S_    = 2048;
static constexpr int D_    = 2048;
static constexpr int NH_   = 32;
static constexpr int NKVH_ = 8;
static constexpr int HD_   = 64;
static constexpr int KVD_  = NKVH_ * HD_;   // 512

using bf16 = __hip_bfloat16;
typedef __attribute__((ext_vector_type(4))) float f32x4;
typedef __attribute__((ext_vector_type(8))) short s16x8;

__device__ inline unsigned short f2bf_bits(float f) {
  bf16 h = __float2bfloat16(f);
  union { bf16 b; unsigned short u; } cv; cv.b = h; return cv.u;
}

// ---------- generic f32 -> bf16 cast, n divisible by 4 ----------
__global__ __launch_bounds__(256) void cast4_kernel(const float* __restrict__ in,
                                                    bf16* __restrict__ out, int n4) {
  int i = blockIdx.x * 256 + threadIdx.x;
  if (i >= n4) return;
  float4 v = reinterpret_cast<const float4*>(in)[i];
  ushort4 o;
  o.x = f2bf_bits(v.x); o.y = f2bf_bits(v.y); o.z = f2bf_bits(v.z); o.w = f2bf_bits(v.w);
  reinterpret_cast<ushort4*>(out)[i] = o;
}

// ---------- bf16 MFMA GEMM: C[M][N] = X[M][K] @ W[N][K]^T (m97 structure) ----------
__device__ inline void gld_lds16(const void* g, void* l) {
  __builtin_amdgcn_global_load_lds((const __attribute__((address_space(1))) void*)g,
                                   (__attribute__((address_space(3))) void*)l, 16, 0, 0);
}

__global__ __launch_bounds__(256) void gemm_bt_kernel(
    const bf16* __restrict__ X, const bf16* __restrict__ W,
    float* __restrict__ C, int M, int N, int K)
{
  __shared__ __align__(16) bf16 As[128 * 32];
  __shared__ __align__(16) bf16 Bs[128 * 32];
  const int tid = threadIdx.x;
  const int lane = tid & 63;
  const int wid = tid >> 6;
  const int m0 = blockIdx.y * 128;
  const int n0 = blockIdx.x * 128;
  const int wm = (wid >> 1) * 64;
  const int wn = (wid & 1) * 64;

  f32x4 acc[4][4] = {};
  const int kg = (lane >> 4) * 8;   // k element offset inside fragment
  const int fr = lane & 15;         // row/col index inside 16-tile

  for (int kt = 0; kt < K; kt += 32) {
    #pragma unroll
    for (int c = 0; c < 2; ++c) {
      int o  = c * 4096 + tid * 16;    // byte offset within 8KB tile
      int r  = o >> 6;                 // tile row (64B per row)
      int ke = (o & 63) >> 1;          // k element within row
      const bf16* srcA = X + (size_t)(m0 + r) * K + kt + ke;
      gld_lds16(srcA, (char*)As + o);
      int wr = n0 + r; if (wr > N - 1) wr = N - 1;   // clamp for N<128 tiles
      const bf16* srcB = W + (size_t)wr * K + kt + ke;
      gld_lds16(srcB, (char*)Bs + o);
    }
    __syncthreads();
    s16x8 af[4], bfr[4];
    #pragma unroll
    for (int i = 0; i < 4; ++i) {
      af[i]  = *reinterpret_cast<const s16x8*>(&As[(wm + i * 16 + fr) * 32 + kg]);
      bfr[i] = *reinterpret_cast<const s16x8*>(&Bs[(wn + i * 16 + fr) * 32 + kg]);
    }
    #pragma unroll
    for (int i = 0; i < 4; ++i)
      #pragma unroll
      for (int j = 0; j < 4; ++j)
        acc[i][j] = __builtin_amdgcn_mfma_f32_16x16x32_bf16(af[i], bfr[j], acc[i][j], 0, 0, 0);
    __syncthreads();
  }

  const int cr = (lane >> 4) * 4;
  const int cc = lane & 15;
  #pragma unroll
  for (int i = 0; i < 4; ++i)
    #pragma unroll
    for (int j = 0; j < 4; ++j) {
      int gn = n0 + wn + j * 16 + cc;
      if (gn >= N) continue;
      #pragma unroll
      for (int r = 0; r < 4; ++r) {
        int gm = m0 + wm + i * 16 + cr + r;
        C[(size_t)gm * N + gn] = acc[i][j][r];
      }
    }
}

// ---------- router softmax: rw[s][8] = softmax(x[s] @ Rt^T) ----------
__device__ inline float tofloat(float v) { return v; }
__device__ inline float tofloat(bf16 v) { return __bfloat162float(v); }

template <typename T>
__global__ __launch_bounds__(256) void router_rw_kernel(const T* __restrict__ X,
    const float* __restrict__ Rt, float* __restrict__ rw) {
  int s = blockIdx.x, t = threadIdx.x;
  float part[8] = {};
  for (int d = t; d < D_; d += 256) {
    float xv = tofloat(X[(size_t)s * D_ + d]);
    #pragma unroll
    for (int e = 0; e < 8; ++e) part[e] += xv * Rt[e * D_ + d];
  }
  #pragma unroll
  for (int e = 0; e < 8; ++e)
    for (int off = 32; off; off >>= 1) part[e] += __shfl_xor(part[e], off);
  __shared__ float red[4][8];
  int w = t >> 6, lane = t & 63;
  if (lane == 0) {
    #pragma unroll
    for (int e = 0; e < 8; ++e) red[w][e] = part[e];
  }
  __syncthreads();
  if (t == 0) {
    float lg[8], mx = -1e30f;
    #pragma unroll
    for (int e = 0; e < 8; ++e) { lg[e] = red[0][e] + red[1][e] + red[2][e] + red[3][e]; mx = fmaxf(mx, lg[e]); }
    float sum = 0.f;
    #pragma unroll
    for (int e = 0; e < 8; ++e) { lg[e] = __expf(lg[e] - mx); sum += lg[e]; }
    float inv = 1.f / sum;
    #pragma unroll
    for (int e = 0; e < 8; ++e) rw[s * 8 + e] = lg[e] * inv;
  }
}

// ---------- Out[s][o] += SCALING * sum_{e,r} rw[s][e]*H[s][e*8+r]*Bw[e][o][r] ----------
__global__ __launch_bounds__(256) void lora_add_kernel(float* __restrict__ Out,
    const float* __restrict__ H, const float* __restrict__ rw,
    const float* __restrict__ Bw, int OUT) {
  int s = blockIdx.x, t = threadIdx.x;
  __shared__ float g[64];
  if (t < 64) g[t] = 4.0f * rw[s * 8 + (t >> 3)] * H[(size_t)s * 64 + t];
  __syncthreads();
  for (int o = t; o < OUT; o += 256) {
    float acc = 0.f;
    #pragma unroll
    for (int er = 0; er < 64; ++er)
      acc += g[er] * Bw[((size_t)(er >> 3) * OUT + o) * 8 + (er & 7)];
    Out[(size_t)s * OUT + o] += acc;
  }
}

// ---------- RoPE (Q pre-scaled by 1/sqrt(HD)=0.125) ----------
__global__ __launch_bounds__(256) void rope_q_kernel(const float* __restrict__ Qf,
    const float* __restrict__ fc, const float* __restrict__ fs, bf16* __restrict__ Qb) {
  int idx = blockIdx.x * 256 + threadIdx.x;   // S*NH*32
  int i = idx & 31, h = (idx >> 5) & 31, s = idx >> 10;
  float c = fc[s * 32 + i], sn = fs[s * 32 + i];
  size_t base = (size_t)s * 2048 + h * 64 + 2 * i;
  float2 v = *reinterpret_cast<const float2*>(Qf + base);
  unsigned o = (unsigned)f2bf_bits((v.x * c - v.y * sn) * 0.125f)
             | ((unsigned)f2bf_bits((v.x * sn + v.y * c) * 0.125f) << 16);
  *reinterpret_cast<unsigned*>(Qb + base) = o;
}

__global__ __launch_bounds__(256) void rope_k_kernel(const float* __restrict__ Kf,
    const float* __restrict__ fc, const float* __restrict__ fs, bf16* __restrict__ Kb) {
  int idx = blockIdx.x * 256 + threadIdx.x;   // S*NKVH*32
  int i = idx & 31, hk = (idx >> 5) & 7, s = idx >> 8;
  float c = fc[s * 32 + i], sn = fs[s * 32 + i];
  size_t base = (size_t)s * KVD_ + hk * 64 + 2 * i;
  float2 v = *reinterpret_cast<const float2*>(Kf + base);
  unsigned o = (unsigned)f2bf_bits(v.x * c - v.y * sn)
             | ((unsigned)f2bf_bits(v.x * sn + v.y * c) << 16);
  *reinterpret_cast<unsigned*>(Kb + base) = o;
}

// ---------- V transpose: Vt[hk][d][s] = bf16(Vf[s][hk*64+d]) ----------
__global__ __launch_bounds__(256) void vt_kernel(const float* __restrict__ Vf,
                                                 bf16* __restrict__ Vt) {
  int idx = blockIdx.x * 256 + threadIdx.x;   // NKVH*64*S, s fastest
  int s = idx & 2047, d = (idx >> 11) & 63, hk = idx >> 17;
  Vt[idx] = __float2bfloat16(Vf[(size_t)s * KVD_ + hk * 64 + d]);
}

// ---------- MFMA flash attention ----------
// Per wave: 32 q rows; KV tiles of 64. Swapped QK (S^T = K·Q^T) so row-reduce
// is in-lane; P transposed via per-wave LDS; swapped PV (O^T = Vt·P^T).
__global__ __launch_bounds__(256) void attn_mfma_kernel(
    const bf16* __restrict__ Q,   // [S][2048], pre-scaled
    const bf16* __restrict__ K,   // [S][512]
    const bf16* __restrict__ Vt,  // [8][64][S]
    bf16* __restrict__ O)         // [S][2048]
{
  __shared__ __align__(16) char p_lds_all[4][32 * 144];
  const int tid  = threadIdx.x;
  const int lane = tid & 63;
  const int wid  = tid >> 6;
  const int fr   = lane & 15;
  const int g    = lane >> 4;
  const int h    = blockIdx.y;
  const int hk   = h >> 2;
  const int qb   = (gridDim.x - 1) - blockIdx.x;   // heavy blocks first
  const int q0   = qb * 128 + wid * 32;
  char* p_lds = p_lds_all[wid];

  // Q fragments (B-frag: col = q uses fr, k = d)
  s16x8 qf[2][2];
  #pragma unroll
  for (int i = 0; i < 2; ++i)
    #pragma unroll
    for (int kc = 0; kc < 2; ++kc)
      qf[i][kc] = *reinterpret_cast<const s16x8*>(
          Q + (size_t)(q0 + i * 16 + fr) * 2048 + h * 64 + kc * 32 + g * 8);

  f32x4 acc[4][2] = {};          // [dt][i]: O^T[d = dt*16 + g*4+r][q = i*16+fr]
  float m[2]    = {-1e30f, -1e30f};
  float lsum[2] = {0.f, 0.f};

  const bf16* Kh  = K  + hk * 64;
  const bf16* Vth = Vt + (size_t)hk * 64 * S_;

  const int ntiles = (q0 + 32 + 63) >> 6;
  const int nomask = (q0 + 1) >> 6;

  for (int t = 0; t < ntiles; ++t) {
    const int k0 = t * 64;

    // ---- QK^T (swapped): st[kt][i] holds S[key=k0+kt*16+g*4+r][q=q0+i*16+fr]
    f32x4 st[4][2] = {};
    __builtin_amdgcn_s_setprio(1);
    #pragma unroll
    for (int kc = 0; kc < 2; ++kc)
      #pragma unroll
      for (int kt = 0; kt < 4; ++kt) {
        s16x8 kf = *reinterpret_cast<const s16x8*>(
            Kh + (size_t)(k0 + kt * 16 + fr) * KVD_ + kc * 32 + g * 8);
        #pragma unroll
        for (int i = 0; i < 2; ++i)
          st[kt][i] = __builtin_amdgcn_mfma_f32_16x16x32_bf16(kf, qf[i][kc], st[kt][i], 0, 0, 0);
      }
    __builtin_amdgcn_s_setprio(0);

    // ---- causal mask (wave-uniform branch)
    if (t >= nomask) {
      #pragma unroll
      for (int kt = 0; kt < 4; ++kt)
        #pragma unroll
        for (int i = 0; i < 2; ++i)
          #pragma unroll
          for (int r = 0; r < 4; ++r) {
            int key = k0 + kt * 16 + g * 4 + r;
            int q   = q0 + i * 16 + fr;
            if (key > q) st[kt][i][r] = -1e30f;
          }
    }

    // ---- online softmax (in-lane over 16 keys + 2 shfls)
    #pragma unroll
    for (int i = 0; i < 2; ++i) {
      float tm = -1e30f;
      #pragma unroll
      for (int kt = 0; kt < 4; ++kt)
        #pragma unroll
        for (int r = 0; r < 4; ++r)
          tm = fmaxf(tm, st[kt][i][r]);
      tm = fmaxf(tm, __shfl_xor(tm, 16));
      tm = fmaxf(tm, __shfl_xor(tm, 32));
      float newm = fmaxf(m[i], tm);
      float rs = __expf(m[i] - newm);
      m[i] = newm;
      lsum[i] *= rs;
      #pragma unroll
      for (int dt = 0; dt < 4; ++dt)
        #pragma unroll
        for (int r = 0; r < 4; ++r)
          acc[dt][i][r] *= rs;
      // p = exp(s - newm), accumulate lsum, pack pairs -> LDS (P[q][key])
      #pragma unroll
      for (int kt = 0; kt < 4; ++kt) {
        float p0 = __expf(st[kt][i][0] - newm);
        float p1 = __expf(st[kt][i][1] - newm);
        float p2 = __expf(st[kt][i][2] - newm);
        float p3 = __expf(st[kt][i][3] - newm);
        lsum[i] += (p0 + p1) + (p2 + p3);
        unsigned w0 = (unsigned)f2bf_bits(p0) | ((unsigned)f2bf_bits(p1) << 16);
        unsigned w1 = (unsigned)f2bf_bits(p2) | ((unsigned)f2bf_bits(p3) << 16);
        char* base = p_lds + (i * 16 + fr) * 144 + (kt * 16 + g * 4) * 2;
        *reinterpret_cast<unsigned*>(base)     = w0;
        *reinterpret_cast<unsigned*>(base + 4) = w1;
      }
    }

    // ---- PV (swapped): acc[dt][i] += Vt-frag x P-frag
    __builtin_amdgcn_s_setprio(1);
    #pragma unroll
    for (int kc = 0; kc < 2; ++kc) {
      s16x8 pf[2];
      #pragma unroll
      for (int i = 0; i < 2; ++i)
        pf[i] = *reinterpret_cast<const s16x8*>(
            p_lds + (i * 16 + fr) * 144 + (kc * 32 + g * 8) * 2);
      #pragma unroll
      for (int dt = 0; dt < 4; ++dt) {
        s16x8 vf = *reinterpret_cast<const s16x8*>(
            Vth + (size_t)(dt * 16 + fr) * S_ + k0 + kc * 32 + g * 8);
        #pragma unroll
        for (int i = 0; i < 2; ++i)
          acc[dt][i] = __builtin_amdgcn_mfma_f32_16x16x32_bf16(vf, pf[i], acc[dt][i], 0, 0, 0);
      }
    }
    __builtin_amdgcn_s_setprio(0);
  }

  // ---- epilogue: O[q][d] = acc/lsum
  #pragma unroll
  for (int i = 0; i < 2; ++i) {
    lsum[i] += __shfl_xor(lsum[i], 16);
    lsum[i] += __shfl_xor(lsum[i], 32);
  }
  float inv0 = 1.f / lsum[0], inv1 = 1.f / lsum[1];
  #pragma unroll
  for (int i = 0; i < 2; ++i) {
    float inv = i ? inv1 : inv0;
    #pragma unroll
    for (int dt = 0; dt < 4; ++dt)
      #pragma unroll
      for (int r2 = 0; r2 < 2; ++r2) {
        unsigned o = (unsigned)f2bf_bits(acc[dt][i][2 * r2] * inv)
                   | ((unsigned)f2bf_bits(acc[dt][i][2 * r2 + 1] * inv) << 16);
        size_t off = (size_t)(q0 + i * 16 + fr) * 2048 + h * 64 + dt * 16 + g * 4 + 2 * r2;
        *reinterpret_cast<unsigned*>(O + off) = o;
      }
  }
}

extern "C" void kernel_launch(void* const* d_in, const int* in_sizes, int n_in,
                              void* d_out, int out_size, void* d_ws, size_t ws_size,
                              hipStream_t stream) {
  const float* x   = (const float*)d_in[0];
  const float* fc  = (const float*)d_in[3];
  const float* fs  = (const float*)d_in[4];
  const float* wq  = (const float*)d_in[5];
  const float* wk  = (const float*)d_in[6];
  const float* wv  = (const float*)d_in[7];
  const float* wo  = (const float*)d_in[8];
  const float* lqR = (const float*)d_in[9];
  const float* lqA = (const float*)d_in[10];
  const float* lqB = (const float*)d_in[11];
  const float* lkR = (const float*)d_in[12];
  const float* lkA = (const float*)d_in[13];
  const float* lkB = (const float*)d_in[14];
  const float* lvR = (const float*)d_in[15];
  const float* lvA = (const float*)d_in[16];
  const float* lvB = (const float*)d_in[17];
  const float* loR = (const float*)d_in[18];
  const float* loA = (const float*)d_in[19];
  const float* loB = (const float*)d_in[20];
  float* out = (float*)d_out;
  char* ws = (char*)d_ws;

  if (ws_size < 58000000u) return;  // workspace too small: bail cleanly

  bf16* xb   = (bf16*)(ws + 0);            // 8MB ; aliased as AOb later
  bf16* wqb  = (bf16*)(ws + 8388608);      // 8MB ; aliased as Qb later
  bf16* wkb  = (bf16*)(ws + 16777216);     // 2MB ; aliased as Kb later
  bf16* wvb  = (bf16*)(ws + 18874368);     // 2MB ; aliased as Vt later
  bf16* wob  = (bf16*)(ws + 20971520);     // 8MB
  bf16* lqAb = (bf16*)(ws + 29360128);     // 256KB
  bf16* lkAb = (bf16*)(ws + 29622272);
  bf16* lvAb = (bf16*)(ws + 29884416);
  bf16* loAb = (bf16*)(ws + 30146560);
  float* Qf  = (float*)(ws + 30408704);    // 16MB
  float* Kf  = (float*)(ws + 47185920);    // 4MB
  float* Vf  = (float*)(ws + 51380224);    // 4MB
  float* Hq  = (float*)(ws + 55574528);    // 512KB
  float* Hk  = (float*)(ws + 56098816);
  float* Hv  = (float*)(ws + 56623104);
  float* Ho  = (float*)(ws + 57147392);
  float* rwq = (float*)(ws + 57671680);    // 64KB each
  float* rwk = (float*)(ws + 57737216);
  float* rwv = (float*)(ws + 57802752);
  float* rwo = (float*)(ws + 57868288);

  bf16* AOb = xb;
  bf16* Qb  = wqb;
  bf16* Kb  = wkb;
  bf16* Vtb = wvb;

  auto cast = [&](const float* src, bf16* dst, int n) {
    cast4_kernel<<<dim3((n / 4 + 255) / 256), dim3(256), 0, stream>>>(src, dst, n / 4);
  };
  cast(x,  xb,  S_ * D_);
  cast(wq, wqb, D_ * D_);
  cast(wk, wkb, KVD_ * D_);
  cast(wv, wvb, KVD_ * D_);
  cast(wo, wob, D_ * D_);
  cast(lqA, lqAb, 64 * D_);
  cast(lkA, lkAb, 64 * D_);
  cast(lvA, lvAb, 64 * D_);
  cast(loA, loAb, 64 * D_);

  auto gemm = [&](const bf16* X_, const bf16* W_, float* C_, int M, int N, int K) {
    gemm_bt_kernel<<<dim3((N + 127) / 128, M / 128), dim3(256), 0, stream>>>(X_, W_, C_, M, N, K);
  };
  gemm(xb, wqb,  Qf, S_, D_,   D_);
  gemm(xb, wkb,  Kf, S_, KVD_, D_);
  gemm(xb, wvb,  Vf, S_, KVD_, D_);
  gemm(xb, lqAb, Hq, S_, 64,   D_);
  gemm(xb, lkAb, Hk, S_, 64,   D_);
  gemm(xb, lvAb, Hv, S_, 64,   D_);

  router_rw_kernel<float><<<dim3(S_), dim3(256), 0, stream>>>(x, lqR, rwq);
  router_rw_kernel<float><<<dim3(S_), dim3(256), 0, stream>>>(x, lkR, rwk);
  router_rw_kernel<float><<<dim3(S_), dim3(256), 0, stream>>>(x, lvR, rwv);

  lora_add_kernel<<<dim3(S_), dim3(256), 0, stream>>>(Qf, Hq, rwq, lqB, D_);
  lora_add_kernel<<<dim3(S_), dim3(256), 0, stream>>>(Kf, Hk, rwk, lkB, KVD_);
  lora_add_kernel<<<dim3(S_), dim3(256), 0, stream>>>(Vf, Hv, rwv, lvB, KVD_);

  rope_q_kernel<<<dim3(S_ * NH_ * 32 / 256),   dim3(256), 0, stream>>>(Qf, fc, fs, Qb);
  rope_k_kernel<<<dim3(S_ * NKVH_ * 32 / 256), dim3(256), 0, stream>>>(Kf, fc, fs, Kb);
  vt_kernel<<<dim3(NKVH_ * 64 * S_ / 256), dim3(256), 0, stream>>>(Vf, Vtb);

  attn_mfma_kernel<<<dim3(S_ / 128, NH_), dim3(256), 0, stream>>>(Qb, Kb, Vtb, AOb);

  router_rw_kernel<bf16><<<dim3(S_), dim3(256), 0, stream>>>(AOb, loR, rwo);
  gemm(AOb, loAb, Ho, S_, 64, D_);
  gemm(AOb, wob,  out, S_, D_, D_);
  lora_add_kernel<<<dim3(S_), dim3(256), 0, stream>>>(out, Ho, rwo, loB, D_);
}

// Round 3
// 558.627 us; speedup vs baseline: 2.8951x; 1.2079x over previous
//
#include <hip/hip_runtime.h>
#include <hip/hip_bf16.h>

static constexpr int S_    = 2048;
static constexpr int D_    = 2048;
static constexpr int NH_   = 32;
static constexpr int NKVH_ = 8;
static constexpr int HD_   = 64;
static constexpr int KVD_  = NKVH_ * HD_;   // 512
static constexpr int NQKV_ = 3288;          // 2048 q + 512 k + 512 v + 192 H + 24 logits
static constexpr int NOUT_ = 2120;          // 2048 o + 64 H + 8 logits

using bf16 = __hip_bfloat16;
typedef __attribute__((ext_vector_type(4))) float f32x4;
typedef __attribute__((ext_vector_type(8))) short s16x8;

__device__ inline unsigned short f2bf_bits(float f) {
  bf16 h = __float2bfloat16(f);
  union { bf16 b; unsigned short u; } cv; cv.b = h; return cv.u;
}
__device__ inline float bfbits2f(unsigned short u) {
  union { unsigned u32; float f; } cv; cv.u32 = (unsigned)u << 16; return cv.f;
}

// ---------- f32 -> bf16 cast ----------
__global__ __launch_bounds__(256) void cast4_kernel(const float* __restrict__ in,
                                                    bf16* __restrict__ out, int n4) {
  int i = blockIdx.x * 256 + threadIdx.x;
  if (i >= n4) return;
  float4 v = reinterpret_cast<const float4*>(in)[i];
  ushort4 o;
  o.x = f2bf_bits(v.x); o.y = f2bf_bits(v.y); o.z = f2bf_bits(v.z); o.w = f2bf_bits(v.w);
  reinterpret_cast<ushort4*>(out)[i] = o;
}

// ---------- weight packing (concat rows, f32 -> bf16), K = 2048 ----------
__global__ __launch_bounds__(256) void pack_qkv_kernel(
    const float* __restrict__ wq, const float* __restrict__ wk, const float* __restrict__ wv,
    const float* __restrict__ lqA, const float* __restrict__ lkA, const float* __restrict__ lvA,
    const float* __restrict__ lqR, const float* __restrict__ lkR, const float* __restrict__ lvR,
    bf16* __restrict__ Wp) {
  int r = blockIdx.x;
  const float* src;
  if      (r < 2048) src = wq  + (size_t)r * 2048;
  else if (r < 2560) src = wk  + (size_t)(r - 2048) * 2048;
  else if (r < 3072) src = wv  + (size_t)(r - 2560) * 2048;
  else if (r < 3136) src = lqA + (size_t)(r - 3072) * 2048;
  else if (r < 3200) src = lkA + (size_t)(r - 3136) * 2048;
  else if (r < 3264) src = lvA + (size_t)(r - 3200) * 2048;
  else if (r < 3272) src = lqR + (size_t)(r - 3264) * 2048;
  else if (r < 3280) src = lkR + (size_t)(r - 3272) * 2048;
  else               src = lvR + (size_t)(r - 3280) * 2048;
  bf16* dst = Wp + (size_t)r * 2048;
  for (int c = threadIdx.x; c < 512; c += 256) {
    float4 v = reinterpret_cast<const float4*>(src)[c];
    ushort4 o;
    o.x = f2bf_bits(v.x); o.y = f2bf_bits(v.y); o.z = f2bf_bits(v.z); o.w = f2bf_bits(v.w);
    reinterpret_cast<ushort4*>(dst)[c] = o;
  }
}

__global__ __launch_bounds__(256) void pack_out_kernel(
    const float* __restrict__ wo, const float* __restrict__ loA,
    const float* __restrict__ loR, bf16* __restrict__ Wp) {
  int r = blockIdx.x;
  const float* src;
  if      (r < 2048) src = wo  + (size_t)r * 2048;
  else if (r < 2112) src = loA + (size_t)(r - 2048) * 2048;
  else               src = loR + (size_t)(r - 2112) * 2048;
  bf16* dst = Wp + (size_t)r * 2048;
  for (int c = threadIdx.x; c < 512; c += 256) {
    float4 v = reinterpret_cast<const float4*>(src)[c];
    ushort4 o;
    o.x = f2bf_bits(v.x); o.y = f2bf_bits(v.y); o.z = f2bf_bits(v.z); o.w = f2bf_bits(v.w);
    reinterpret_cast<ushort4*>(dst)[c] = o;
  }
}

// ---------- bf16 MFMA GEMM: C[M][N] = X[M][K] @ W[N][K]^T (m97 structure) ----------
__device__ inline void gld_lds16(const void* g, void* l) {
  __builtin_amdgcn_global_load_lds((const __attribute__((address_space(1))) void*)g,
                                   (__attribute__((address_space(3))) void*)l, 16, 0, 0);
}

template <typename OT>
__global__ __launch_bounds__(256) void gemm_bt_kernel(
    const bf16* __restrict__ X, const bf16* __restrict__ W,
    OT* __restrict__ C, int M, int N, int K)
{
  __shared__ __align__(16) bf16 As[128 * 32];
  __shared__ __align__(16) bf16 Bs[128 * 32];
  const int tid = threadIdx.x;
  const int lane = tid & 63;
  const int wid = tid >> 6;
  const int m0 = blockIdx.y * 128;
  const int n0 = blockIdx.x * 128;
  const int wm = (wid >> 1) * 64;
  const int wn = (wid & 1) * 64;

  f32x4 acc[4][4] = {};
  const int kg = (lane >> 4) * 8;
  const int fr = lane & 15;

  for (int kt = 0; kt < K; kt += 32) {
    #pragma unroll
    for (int c = 0; c < 2; ++c) {
      int o  = c * 4096 + tid * 16;
      int r  = o >> 6;
      int ke = (o & 63) >> 1;
      const bf16* srcA = X + (size_t)(m0 + r) * K + kt + ke;
      gld_lds16(srcA, (char*)As + o);
      int wr = n0 + r; if (wr > N - 1) wr = N - 1;
      const bf16* srcB = W + (size_t)wr * K + kt + ke;
      gld_lds16(srcB, (char*)Bs + o);
    }
    __syncthreads();
    s16x8 af[4], bfr[4];
    #pragma unroll
    for (int i = 0; i < 4; ++i) {
      af[i]  = *reinterpret_cast<const s16x8*>(&As[(wm + i * 16 + fr) * 32 + kg]);
      bfr[i] = *reinterpret_cast<const s16x8*>(&Bs[(wn + i * 16 + fr) * 32 + kg]);
    }
    #pragma unroll
    for (int i = 0; i < 4; ++i)
      #pragma unroll
      for (int j = 0; j < 4; ++j)
        acc[i][j] = __builtin_amdgcn_mfma_f32_16x16x32_bf16(af[i], bfr[j], acc[i][j], 0, 0, 0);
    __syncthreads();
  }

  const int cr = (lane >> 4) * 4;
  const int cc = lane & 15;
  #pragma unroll
  for (int i = 0; i < 4; ++i)
    #pragma unroll
    for (int j = 0; j < 4; ++j) {
      int gn = n0 + wn + j * 16 + cc;
      if (gn >= N) continue;
      #pragma unroll
      for (int r = 0; r < 4; ++r) {
        int gm = m0 + wm + i * 16 + cr + r;
        if constexpr (__is_same(OT, bf16))
          C[(size_t)gm * N + gn] = __float2bfloat16(acc[i][j][r]);
        else
          C[(size_t)gm * N + gn] = acc[i][j][r];
      }
    }
}

// ---------- QKV epilogue: softmax(router) + LoRA-B + RoPE + bf16 writes ----------
// C1[s][NQKV_] bf16: [0,2048)=q, [2048,2560)=k, [2560,3072)=v,
// [3072,3264)=H(q,k,v), [3264,3288)=logits(q,k,v).  8 s-rows per block.
__global__ __launch_bounds__(512) void qkv_epilogue_kernel(
    const bf16* __restrict__ C1, const float* __restrict__ fc, const float* __restrict__ fs,
    const float* __restrict__ lqB, const float* __restrict__ lkB, const float* __restrict__ lvB,
    bf16* __restrict__ Qb, bf16* __restrict__ Kb, bf16* __restrict__ Vb)
{
  const int s0 = blockIdx.x * 8;
  const int t = threadIdx.x;
  __shared__ float lg[8][24];
  __shared__ __align__(16) float G[8][192];

  if (t < 192) {
    int si = t / 24, c = t % 24;
    lg[si][c] = bfbits2f(reinterpret_cast<const unsigned short*>(C1)[(size_t)(s0 + si) * NQKV_ + 3264 + c]);
  }
  __syncthreads();
  if (t < 24) {
    int si = t / 3, seg = t % 3;
    float* l = &lg[si][seg * 8];
    float mx = l[0];
    #pragma unroll
    for (int e = 1; e < 8; ++e) mx = fmaxf(mx, l[e]);
    float sum = 0.f;
    #pragma unroll
    for (int e = 0; e < 8; ++e) { l[e] = __expf(l[e] - mx); sum += l[e]; }
    float inv = 1.f / sum;
    #pragma unroll
    for (int e = 0; e < 8; ++e) l[e] *= inv;
  }
  __syncthreads();
  for (int k = t; k < 1536; k += 512) {
    int si = k / 192, j = k % 192;
    int seg = j >> 6, e = (j & 63) >> 3;
    G[si][j] = 4.f * lg[si][seg * 8 + e] *
               bfbits2f(reinterpret_cast<const unsigned short*>(C1)[(size_t)(s0 + si) * NQKV_ + 3072 + j]);
  }
  __syncthreads();

  #pragma unroll
  for (int pc = 0; pc < 3; ++pc) {
    int p = pc * 512 + t;         // pair index, 0..1535
    int col = 2 * p;
    int seg, ol, goff, OUT;
    const float* Bp;
    if (col < 2048)      { seg = 0; ol = col;        Bp = lqB; goff = 0;   OUT = 2048; }
    else if (col < 2560) { seg = 1; ol = col - 2048; Bp = lkB; goff = 64;  OUT = 512; }
    else                 { seg = 2; ol = col - 2560; Bp = lvB; goff = 128; OUT = 512; }

    float a0[8] = {}, a1[8] = {};
    const float4* B4 = reinterpret_cast<const float4*>(Bp);
    #pragma unroll
    for (int e = 0; e < 8; ++e) {
      size_t bi = ((size_t)e * OUT + ol) * 2;
      float4 b0a = B4[bi], b0b = B4[bi + 1], b1a = B4[bi + 2], b1b = B4[bi + 3];
      #pragma unroll
      for (int si = 0; si < 8; ++si) {
        float4 g0 = *reinterpret_cast<const float4*>(&G[si][goff + e * 8]);
        float4 g1 = *reinterpret_cast<const float4*>(&G[si][goff + e * 8 + 4]);
        a0[si] += g0.x * b0a.x + g0.y * b0a.y + g0.z * b0a.z + g0.w * b0a.w
                + g1.x * b0b.x + g1.y * b0b.y + g1.z * b0b.z + g1.w * b0b.w;
        a1[si] += g0.x * b1a.x + g0.y * b1a.y + g0.z * b1a.z + g0.w * b1a.w
                + g1.x * b1b.x + g1.y * b1b.y + g1.z * b1b.z + g1.w * b1b.w;
      }
    }

    #pragma unroll
    for (int si = 0; si < 8; ++si) {
      size_t row = (size_t)(s0 + si);
      unsigned base = *reinterpret_cast<const unsigned*>(&C1[row * NQKV_ + col]);
      float v0 = bfbits2f((unsigned short)(base & 0xffff)) + a0[si];
      float v1 = bfbits2f((unsigned short)(base >> 16))    + a1[si];
      if (seg == 0) {
        int i = (ol >> 1) & 31;
        float c = fc[row * 32 + i], sn = fs[row * 32 + i];
        unsigned o = (unsigned)f2bf_bits((v0 * c - v1 * sn) * 0.125f)
                   | ((unsigned)f2bf_bits((v0 * sn + v1 * c) * 0.125f) << 16);
        *reinterpret_cast<unsigned*>(&Qb[row * 2048 + ol]) = o;
      } else if (seg == 1) {
        int i = (ol >> 1) & 31;
        float c = fc[row * 32 + i], sn = fs[row * 32 + i];
        unsigned o = (unsigned)f2bf_bits(v0 * c - v1 * sn)
                   | ((unsigned)f2bf_bits(v0 * sn + v1 * c) << 16);
        *reinterpret_cast<unsigned*>(&Kb[row * 512 + ol]) = o;
      } else {
        unsigned o = (unsigned)f2bf_bits(v0) | ((unsigned)f2bf_bits(v1) << 16);
        *reinterpret_cast<unsigned*>(&Vb[row * 512 + ol]) = o;
      }
    }
  }
}

// ---------- output epilogue: out = C2_base + lora_o ----------
__global__ __launch_bounds__(512) void out_epilogue_kernel(
    const float* __restrict__ C2, const float* __restrict__ loB, float* __restrict__ out)
{
  const int s0 = blockIdx.x * 8;
  const int t = threadIdx.x;
  __shared__ float lg[8][8];
  __shared__ __align__(16) float G[8][64];

  if (t < 64) {
    int si = t >> 3, e = t & 7;
    lg[si][e] = C2[(size_t)(s0 + si) * NOUT_ + 2112 + e];
  }
  __syncthreads();
  if (t < 8) {
    float* l = lg[t];
    float mx = l[0];
    #pragma unroll
    for (int e = 1; e < 8; ++e) mx = fmaxf(mx, l[e]);
    float sum = 0.f;
    #pragma unroll
    for (int e = 0; e < 8; ++e) { l[e] = __expf(l[e] - mx); sum += l[e]; }
    float inv = 1.f / sum;
    #pragma unroll
    for (int e = 0; e < 8; ++e) l[e] *= inv;
  }
  __syncthreads();
  if (t < 512) {
    int si = t >> 6, er = t & 63;
    G[si][er] = 4.f * lg[si][er >> 3] * C2[(size_t)(s0 + si) * NOUT_ + 2048 + er];
  }
  __syncthreads();

  const float4* B4 = reinterpret_cast<const float4*>(loB);
  #pragma unroll
  for (int oc = 0; oc < 4; ++oc) {
    int o = oc * 512 + t;
    float a[8] = {};
    #pragma unroll
    for (int e = 0; e < 8; ++e) {
      size_t bi = ((size_t)e * 2048 + o) * 2;
      float4 b0 = B4[bi], b1 = B4[bi + 1];
      #pragma unroll
      for (int si = 0; si < 8; ++si) {
        float4 g0 = *reinterpret_cast<const float4*>(&G[si][e * 8]);
        float4 g1 = *reinterpret_cast<const float4*>(&G[si][e * 8 + 4]);
        a[si] += g0.x * b0.x + g0.y * b0.y + g0.z * b0.z + g0.w * b0.w
               + g1.x * b1.x + g1.y * b1.y + g1.z * b1.z + g1.w * b1.w;
      }
    }
    #pragma unroll
    for (int si = 0; si < 8; ++si) {
      size_t row = (size_t)(s0 + si);
      out[row * 2048 + o] = C2[row * NOUT_ + o] + a[si];
    }
  }
}

// ---------- V transpose: Vt[hk][d][s] = Vb[s][hk*64+d] ----------
__global__ __launch_bounds__(256) void vt_kernel(const bf16* __restrict__ Vb,
                                                 bf16* __restrict__ Vt) {
  int idx = blockIdx.x * 256 + threadIdx.x;   // NKVH*64*S, s fastest
  int s = idx & 2047, d = (idx >> 11) & 63, hk = idx >> 17;
  Vt[idx] = Vb[(size_t)s * KVD_ + hk * 64 + d];
}

// ---------- MFMA flash attention: 1 wave per (32 q rows, head) ----------
__global__ __launch_bounds__(64, 4) void attn_mfma_kernel(
    const bf16* __restrict__ Q,   // [S][2048], pre-scaled
    const bf16* __restrict__ K,   // [S][512]
    const bf16* __restrict__ Vt,  // [8][64][S]
    bf16* __restrict__ O)         // [S][2048]
{
  __shared__ __align__(16) char p_lds[32 * 144];
  const int lane = threadIdx.x;
  const int fr   = lane & 15;
  const int g    = lane >> 4;
  const int h    = blockIdx.y;
  const int hk   = h >> 2;
  const int qb   = (gridDim.x - 1) - blockIdx.x;   // heavy blocks first
  const int q0   = qb * 32;

  s16x8 qf[2][2];
  #pragma unroll
  for (int i = 0; i < 2; ++i)
    #pragma unroll
    for (int kc = 0; kc < 2; ++kc)
      qf[i][kc] = *reinterpret_cast<const s16x8*>(
          Q + (size_t)(q0 + i * 16 + fr) * 2048 + h * 64 + kc * 32 + g * 8);

  f32x4 acc[4][2] = {};
  float m[2]    = {-1e30f, -1e30f};
  float lsum[2] = {0.f, 0.f};

  const bf16* Kh  = K  + hk * 64;
  const bf16* Vth = Vt + (size_t)hk * 64 * S_;

  const int ntiles = (q0 + 32 + 63) >> 6;
  const int nomask = (q0 + 1) >> 6;

  for (int t = 0; t < ntiles; ++t) {
    const int k0 = t * 64;

    f32x4 st[4][2] = {};
    __builtin_amdgcn_s_setprio(1);
    #pragma unroll
    for (int kc = 0; kc < 2; ++kc)
      #pragma unroll
      for (int kt = 0; kt < 4; ++kt) {
        s16x8 kf = *reinterpret_cast<const s16x8*>(
            Kh + (size_t)(k0 + kt * 16 + fr) * KVD_ + kc * 32 + g * 8);
        #pragma unroll
        for (int i = 0; i < 2; ++i)
          st[kt][i] = __builtin_amdgcn_mfma_f32_16x16x32_bf16(kf, qf[i][kc], st[kt][i], 0, 0, 0);
      }
    __builtin_amdgcn_s_setprio(0);

    if (t >= nomask) {
      #pragma unroll
      for (int kt = 0; kt < 4; ++kt)
        #pragma unroll
        for (int i = 0; i < 2; ++i)
          #pragma unroll
          for (int r = 0; r < 4; ++r) {
            int key = k0 + kt * 16 + g * 4 + r;
            int q   = q0 + i * 16 + fr;
            if (key > q) st[kt][i][r] = -1e30f;
          }
    }

    #pragma unroll
    for (int i = 0; i < 2; ++i) {
      float tm = -1e30f;
      #pragma unroll
      for (int kt = 0; kt < 4; ++kt)
        #pragma unroll
        for (int r = 0; r < 4; ++r)
          tm = fmaxf(tm, st[kt][i][r]);
      tm = fmaxf(tm, __shfl_xor(tm, 16));
      tm = fmaxf(tm, __shfl_xor(tm, 32));
      float newm = fmaxf(m[i], tm);
      float rs = __expf(m[i] - newm);
      m[i] = newm;
      lsum[i] *= rs;
      #pragma unroll
      for (int dt = 0; dt < 4; ++dt)
        #pragma unroll
        for (int r = 0; r < 4; ++r)
          acc[dt][i][r] *= rs;
      #pragma unroll
      for (int kt = 0; kt < 4; ++kt) {
        float p0 = __expf(st[kt][i][0] - newm);
        float p1 = __expf(st[kt][i][1] - newm);
        float p2 = __expf(st[kt][i][2] - newm);
        float p3 = __expf(st[kt][i][3] - newm);
        lsum[i] += (p0 + p1) + (p2 + p3);
        unsigned w0 = (unsigned)f2bf_bits(p0) | ((unsigned)f2bf_bits(p1) << 16);
        unsigned w1 = (unsigned)f2bf_bits(p2) | ((unsigned)f2bf_bits(p3) << 16);
        char* base = p_lds + (i * 16 + fr) * 144 + (kt * 16 + g * 4) * 2;
        *reinterpret_cast<unsigned*>(base)     = w0;
        *reinterpret_cast<unsigned*>(base + 4) = w1;
      }
    }

    __builtin_amdgcn_s_setprio(1);
    #pragma unroll
    for (int kc = 0; kc < 2; ++kc) {
      s16x8 pf[2];
      #pragma unroll
      for (int i = 0; i < 2; ++i)
        pf[i] = *reinterpret_cast<const s16x8*>(
            p_lds + (i * 16 + fr) * 144 + (kc * 32 + g * 8) * 2);
      #pragma unroll
      for (int dt = 0; dt < 4; ++dt) {
        s16x8 vf = *reinterpret_cast<const s16x8*>(
            Vth + (size_t)(dt * 16 + fr) * S_ + k0 + kc * 32 + g * 8);
        #pragma unroll
        for (int i = 0; i < 2; ++i)
          acc[dt][i] = __builtin_amdgcn_mfma_f32_16x16x32_bf16(vf, pf[i], acc[dt][i], 0, 0, 0);
      }
    }
    __builtin_amdgcn_s_setprio(0);
  }

  #pragma unroll
  for (int i = 0; i < 2; ++i) {
    lsum[i] += __shfl_xor(lsum[i], 16);
    lsum[i] += __shfl_xor(lsum[i], 32);
  }
  float inv0 = 1.f / lsum[0], inv1 = 1.f / lsum[1];
  #pragma unroll
  for (int i = 0; i < 2; ++i) {
    float inv = i ? inv1 : inv0;
    #pragma unroll
    for (int dt = 0; dt < 4; ++dt)
      #pragma unroll
      for (int r2 = 0; r2 < 2; ++r2) {
        unsigned o = (unsigned)f2bf_bits(acc[dt][i][2 * r2] * inv)
                   | ((unsigned)f2bf_bits(acc[dt][i][2 * r2 + 1] * inv) << 16);
        size_t off = (size_t)(q0 + i * 16 + fr) * 2048 + h * 64 + dt * 16 + g * 4 + 2 * r2;
        *reinterpret_cast<unsigned*>(O + off) = o;
      }
  }
}

extern "C" void kernel_launch(void* const* d_in, const int* in_sizes, int n_in,
                              void* d_out, int out_size, void* d_ws, size_t ws_size,
                              hipStream_t stream) {
  const float* x   = (const float*)d_in[0];
  const float* fc  = (const float*)d_in[3];
  const float* fs  = (const float*)d_in[4];
  const float* wq  = (const float*)d_in[5];
  const float* wk  = (const float*)d_in[6];
  const float* wv  = (const float*)d_in[7];
  const float* wo  = (const float*)d_in[8];
  const float* lqR = (const float*)d_in[9];
  const float* lqA = (const float*)d_in[10];
  const float* lqB = (const float*)d_in[11];
  const float* lkR = (const float*)d_in[12];
  const float* lkA = (const float*)d_in[13];
  const float* lkB = (const float*)d_in[14];
  const float* lvR = (const float*)d_in[15];
  const float* lvA = (const float*)d_in[16];
  const float* lvB = (const float*)d_in[17];
  const float* loR = (const float*)d_in[18];
  const float* loA = (const float*)d_in[19];
  const float* loB = (const float*)d_in[20];
  float* out = (float*)d_out;
  char* ws = (char*)d_ws;

  if (ws_size < 58000000u) return;

  // layout (bytes):
  bf16* xb   = (bf16*)(ws + 0);            // 8 MB; aliased as AOb after gemm1
  bf16* Wqkv = (bf16*)(ws + 8388608);      // 13.47 MB; aliased as Wout after gemm1
  bf16* Qb   = (bf16*)(ws + 21856256);     // 8 MB
  bf16* Kb   = (bf16*)(ws + 30244864);     // 2 MB
  bf16* Vb   = (bf16*)(ws + 32342016);     // 2 MB
  bf16* Vt   = (bf16*)(ws + 34439168);     // 2 MB
  bf16* C1   = (bf16*)(ws + 36536320);     // 13.47 MB (dead after epilogue)
  float* C2  = (float*)(ws + 21856256);    // 17.37 MB, overlays Qb..C1-head (all dead)
  bf16* AOb  = xb;
  bf16* Wout = Wqkv;

  cast4_kernel<<<dim3(S_ * D_ / 4 / 256), dim3(256), 0, stream>>>(x, xb, S_ * D_ / 4);
  pack_qkv_kernel<<<dim3(NQKV_), dim3(256), 0, stream>>>(wq, wk, wv, lqA, lkA, lvA,
                                                         lqR, lkR, lvR, Wqkv);
  gemm_bt_kernel<bf16><<<dim3((NQKV_ + 127) / 128, S_ / 128), dim3(256), 0, stream>>>(
      xb, Wqkv, C1, S_, NQKV_, D_);
  qkv_epilogue_kernel<<<dim3(S_ / 8), dim3(512), 0, stream>>>(C1, fc, fs, lqB, lkB, lvB,
                                                              Qb, Kb, Vb);
  vt_kernel<<<dim3(NKVH_ * 64 * S_ / 256), dim3(256), 0, stream>>>(Vb, Vt);
  attn_mfma_kernel<<<dim3(S_ / 32, NH_), dim3(64), 0, stream>>>(Qb, Kb, Vt, AOb);
  pack_out_kernel<<<dim3(NOUT_), dim3(256), 0, stream>>>(wo, loA, loR, Wout);
  gemm_bt_kernel<float><<<dim3((NOUT_ + 127) / 128, S_ / 128), dim3(256), 0, stream>>>(
      AOb, Wout, C2, S_, NOUT_, D_);
  out_epilogue_kernel<<<dim3(S_ / 8), dim3(512), 0, stream>>>(C2, loB, out);
}

// Round 4
// 358.157 us; speedup vs baseline: 4.5156x; 1.5597x over previous
//
#include <hip/hip_runtime.h>
#include <hip/hip_bf16.h>

static constexpr int S_    = 2048;
static constexpr int D_    = 2048;
static constexpr int NH_   = 32;
static constexpr int NKVH_ = 8;
static constexpr int HD_   = 64;
static constexpr int KVD_  = NKVH_ * HD_;   // 512
static constexpr int NQKV_ = 3288;          // 2048 q + 512 k + 512 v + 192 H + 24 logits
static constexpr int NOUT_ = 2120;          // 2048 o + 64 H + 8 logits

using bf16 = __hip_bfloat16;
typedef __attribute__((ext_vector_type(4))) float f32x4;
typedef __attribute__((ext_vector_type(8))) short s16x8;

__device__ inline unsigned short f2bf_bits(float f) {
  bf16 h = __float2bfloat16(f);
  union { bf16 b; unsigned short u; } cv; cv.b = h; return cv.u;
}
__device__ inline float bfbits2f(unsigned short u) {
  union { unsigned u32; float f; } cv; cv.u32 = (unsigned)u << 16; return cv.f;
}

// ---------- f32 -> bf16 cast ----------
__global__ __launch_bounds__(256) void cast4_kernel(const float* __restrict__ in,
                                                    bf16* __restrict__ out, int n4) {
  int i = blockIdx.x * 256 + threadIdx.x;
  if (i >= n4) return;
  float4 v = reinterpret_cast<const float4*>(in)[i];
  ushort4 o;
  o.x = f2bf_bits(v.x); o.y = f2bf_bits(v.y); o.z = f2bf_bits(v.z); o.w = f2bf_bits(v.w);
  reinterpret_cast<ushort4*>(out)[i] = o;
}

// ---------- weight packing (concat rows, f32 -> bf16), K = 2048 ----------
__global__ __launch_bounds__(256) void pack_qkv_kernel(
    const float* __restrict__ wq, const float* __restrict__ wk, const float* __restrict__ wv,
    const float* __restrict__ lqA, const float* __restrict__ lkA, const float* __restrict__ lvA,
    const float* __restrict__ lqR, const float* __restrict__ lkR, const float* __restrict__ lvR,
    bf16* __restrict__ Wp) {
  int r = blockIdx.x;
  const float* src;
  if      (r < 2048) src = wq  + (size_t)r * 2048;
  else if (r < 2560) src = wk  + (size_t)(r - 2048) * 2048;
  else if (r < 3072) src = wv  + (size_t)(r - 2560) * 2048;
  else if (r < 3136) src = lqA + (size_t)(r - 3072) * 2048;
  else if (r < 3200) src = lkA + (size_t)(r - 3136) * 2048;
  else if (r < 3264) src = lvA + (size_t)(r - 3200) * 2048;
  else if (r < 3272) src = lqR + (size_t)(r - 3264) * 2048;
  else if (r < 3280) src = lkR + (size_t)(r - 3272) * 2048;
  else               src = lvR + (size_t)(r - 3280) * 2048;
  bf16* dst = Wp + (size_t)r * 2048;
  for (int c = threadIdx.x; c < 512; c += 256) {
    float4 v = reinterpret_cast<const float4*>(src)[c];
    ushort4 o;
    o.x = f2bf_bits(v.x); o.y = f2bf_bits(v.y); o.z = f2bf_bits(v.z); o.w = f2bf_bits(v.w);
    reinterpret_cast<ushort4*>(dst)[c] = o;
  }
}

__global__ __launch_bounds__(256) void pack_out_kernel(
    const float* __restrict__ wo, const float* __restrict__ loA,
    const float* __restrict__ loR, bf16* __restrict__ Wp) {
  int r = blockIdx.x;
  const float* src;
  if      (r < 2048) src = wo  + (size_t)r * 2048;
  else if (r < 2112) src = loA + (size_t)(r - 2048) * 2048;
  else               src = loR + (size_t)(r - 2112) * 2048;
  bf16* dst = Wp + (size_t)r * 2048;
  for (int c = threadIdx.x; c < 512; c += 256) {
    float4 v = reinterpret_cast<const float4*>(src)[c];
    ushort4 o;
    o.x = f2bf_bits(v.x); o.y = f2bf_bits(v.y); o.z = f2bf_bits(v.z); o.w = f2bf_bits(v.w);
    reinterpret_cast<ushort4*>(dst)[c] = o;
  }
}

// ---------- bf16 MFMA GEMM: C[M][N] = X[M][K] @ W[N][K]^T (m97 structure) ----------
__device__ inline void gld_lds16(const void* g, void* l) {
  __builtin_amdgcn_global_load_lds((const __attribute__((address_space(1))) void*)g,
                                   (__attribute__((address_space(3))) void*)l, 16, 0, 0);
}

template <typename OT>
__global__ __launch_bounds__(256) void gemm_bt_kernel(
    const bf16* __restrict__ X, const bf16* __restrict__ W,
    OT* __restrict__ C, int M, int N, int K)
{
  __shared__ __align__(16) bf16 As[128 * 32];
  __shared__ __align__(16) bf16 Bs[128 * 32];
  const int tid = threadIdx.x;
  const int lane = tid & 63;
  const int wid = tid >> 6;
  const int m0 = blockIdx.y * 128;
  const int n0 = blockIdx.x * 128;
  const int wm = (wid >> 1) * 64;
  const int wn = (wid & 1) * 64;

  f32x4 acc[4][4] = {};
  const int kg = (lane >> 4) * 8;
  const int fr = lane & 15;

  for (int kt = 0; kt < K; kt += 32) {
    #pragma unroll
    for (int c = 0; c < 2; ++c) {
      int o  = c * 4096 + tid * 16;
      int r  = o >> 6;
      int ke = (o & 63) >> 1;
      const bf16* srcA = X + (size_t)(m0 + r) * K + kt + ke;
      gld_lds16(srcA, (char*)As + o);
      int wr = n0 + r; if (wr > N - 1) wr = N - 1;
      const bf16* srcB = W + (size_t)wr * K + kt + ke;
      gld_lds16(srcB, (char*)Bs + o);
    }
    __syncthreads();
    s16x8 af[4], bfr[4];
    #pragma unroll
    for (int i = 0; i < 4; ++i) {
      af[i]  = *reinterpret_cast<const s16x8*>(&As[(wm + i * 16 + fr) * 32 + kg]);
      bfr[i] = *reinterpret_cast<const s16x8*>(&Bs[(wn + i * 16 + fr) * 32 + kg]);
    }
    #pragma unroll
    for (int i = 0; i < 4; ++i)
      #pragma unroll
      for (int j = 0; j < 4; ++j)
        acc[i][j] = __builtin_amdgcn_mfma_f32_16x16x32_bf16(af[i], bfr[j], acc[i][j], 0, 0, 0);
    __syncthreads();
  }

  const int cr = (lane >> 4) * 4;
  const int cc = lane & 15;
  #pragma unroll
  for (int i = 0; i < 4; ++i)
    #pragma unroll
    for (int j = 0; j < 4; ++j) {
      int gn = n0 + wn + j * 16 + cc;
      if (gn >= N) continue;
      #pragma unroll
      for (int r = 0; r < 4; ++r) {
        int gm = m0 + wm + i * 16 + cr + r;
        if constexpr (__is_same(OT, bf16))
          C[(size_t)gm * N + gn] = __float2bfloat16(acc[i][j][r]);
        else
          C[(size_t)gm * N + gn] = acc[i][j][r];
      }
    }
}

// ---------- QKV epilogue v2: 2-D tiled, B staged in LDS ----------
// Block = 128 pair-cols x 128 rows. Grid (12, 16). bx 0-7:q, 8-9:k, 10-11:v.
__global__ __launch_bounds__(256) void qkv_epilogue2_kernel(
    const bf16* __restrict__ C1, const float* __restrict__ fc, const float* __restrict__ fs,
    const float* __restrict__ lqB, const float* __restrict__ lkB, const float* __restrict__ lvB,
    bf16* __restrict__ Qb, bf16* __restrict__ Kb, bf16* __restrict__ Vb)
{
  __shared__ float sm[128][8];
  __shared__ __align__(16) float Gt[64][132];   // [er][si], pitch 132 for f4 align
  __shared__ __align__(16) float2 Bs[64][128];  // [er][pair] = {col0, col1}
  const int bx = blockIdx.x;
  const int r0 = blockIdx.y * 128;
  const int t  = threadIdx.x;
  int seg, OUT, opbase; const float* Bp;
  if (bx < 8)       { seg = 0; OUT = 2048; opbase = bx * 128;        Bp = lqB; }
  else if (bx < 10) { seg = 1; OUT = 512;  opbase = (bx - 8) * 128;  Bp = lkB; }
  else              { seg = 2; OUT = 512;  opbase = (bx - 10) * 128; Bp = lvB; }

  const unsigned short* C1u = reinterpret_cast<const unsigned short*>(C1);

  // phase 1: per-row router softmax (x 4.0 scaling folded in)
  if (t < 128) {
    const unsigned short* lp = C1u + (size_t)(r0 + t) * NQKV_ + 3264 + seg * 8;
    float l[8], mx = -1e30f;
    #pragma unroll
    for (int e = 0; e < 8; ++e) { l[e] = bfbits2f(lp[e]); mx = fmaxf(mx, l[e]); }
    float sum = 0.f;
    #pragma unroll
    for (int e = 0; e < 8; ++e) { l[e] = __expf(l[e] - mx); sum += l[e]; }
    float inv = 4.0f / sum;
    #pragma unroll
    for (int e = 0; e < 8; ++e) sm[t][e] = l[e] * inv;
  }
  __syncthreads();

  // phase 2: Gt[er][si] = sm[si][e] * H[si][er]
  #pragma unroll
  for (int k = 0; k < 32; ++k) {
    int idx = t + k * 256;
    int er = idx & 63, si = idx >> 6;
    float h = bfbits2f(C1u[(size_t)(r0 + si) * NQKV_ + 3072 + seg * 64 + er]);
    Gt[er][si] = sm[si][er >> 3] * h;
  }
  // phase 3: stage B slice
  const float4* B4 = reinterpret_cast<const float4*>(Bp);
  #pragma unroll
  for (int k = 0; k < 16; ++k) {
    int idx = t + k * 256;              // 4096 float4s
    int e = idx >> 9, j = idx & 511;
    int pi = j >> 2, q4 = j & 3;
    float4 v = B4[(size_t)(e * OUT + 2 * (opbase + pi)) * 2 + q4];
    int half = q4 >> 1, rbase = (q4 & 1) * 4;
    #pragma unroll
    for (int rr = 0; rr < 4; ++rr)
      reinterpret_cast<float*>(&Bs[e * 8 + rbase + rr][pi])[half] = (&v.x)[rr];
  }
  __syncthreads();

  // phase 4: compute + epilogue. thread = (pair pi, row-half rh)
  const int pi = t & 127, rh = t >> 7;
  const int colC1 = 2 * (128 * bx + pi);
  const int ocol = 2 * (opbase + pi);
  const int hdp = pi & 31;              // head-dim pair index (seg 0/1)
  for (int rb = 0; rb < 8; ++rb) {
    const int sib = rh * 64 + rb * 8;
    float2 acc[8] = {};
    #pragma unroll 8
    for (int er = 0; er < 64; ++er) {
      float2 b = Bs[er][pi];
      float4 ga = *reinterpret_cast<const float4*>(&Gt[er][sib]);
      float4 gb = *reinterpret_cast<const float4*>(&Gt[er][sib + 4]);
      acc[0].x += ga.x * b.x; acc[0].y += ga.x * b.y;
      acc[1].x += ga.y * b.x; acc[1].y += ga.y * b.y;
      acc[2].x += ga.z * b.x; acc[2].y += ga.z * b.y;
      acc[3].x += ga.w * b.x; acc[3].y += ga.w * b.y;
      acc[4].x += gb.x * b.x; acc[4].y += gb.x * b.y;
      acc[5].x += gb.y * b.x; acc[5].y += gb.y * b.y;
      acc[6].x += gb.z * b.x; acc[6].y += gb.z * b.y;
      acc[7].x += gb.w * b.x; acc[7].y += gb.w * b.y;
    }
    #pragma unroll
    for (int rr = 0; rr < 8; ++rr) {
      size_t row = (size_t)(r0 + sib + rr);
      unsigned base = *reinterpret_cast<const unsigned*>(&C1u[row * NQKV_ + colC1]);
      float v0 = bfbits2f((unsigned short)(base & 0xffff)) + acc[rr].x;
      float v1 = bfbits2f((unsigned short)(base >> 16))    + acc[rr].y;
      if (seg == 0) {
        float c = fc[row * 32 + hdp], sn = fs[row * 32 + hdp];
        unsigned o = (unsigned)f2bf_bits((v0 * c - v1 * sn) * 0.125f)
                   | ((unsigned)f2bf_bits((v0 * sn + v1 * c) * 0.125f) << 16);
        *reinterpret_cast<unsigned*>(&Qb[row * 2048 + ocol]) = o;
      } else if (seg == 1) {
        float c = fc[row * 32 + hdp], sn = fs[row * 32 + hdp];
        unsigned o = (unsigned)f2bf_bits(v0 * c - v1 * sn)
                   | ((unsigned)f2bf_bits(v0 * sn + v1 * c) << 16);
        *reinterpret_cast<unsigned*>(&Kb[row * 512 + ocol]) = o;
      } else {
        unsigned o = (unsigned)f2bf_bits(v0) | ((unsigned)f2bf_bits(v1) << 16);
        *reinterpret_cast<unsigned*>(&Vb[row * 512 + ocol]) = o;
      }
    }
  }
}

// ---------- output epilogue v2: 2-D tiled, loB staged in LDS ----------
__global__ __launch_bounds__(256) void out_epilogue2_kernel(
    const float* __restrict__ C2, const float* __restrict__ loB, float* __restrict__ out)
{
  __shared__ float sm[128][8];
  __shared__ __align__(16) float Gt[64][132];
  __shared__ __align__(16) float2 Bs[64][128];
  const int bx = blockIdx.x;            // 0..7
  const int r0 = blockIdx.y * 128;
  const int t  = threadIdx.x;
  const int opbase = bx * 128;

  if (t < 128) {
    const float* lp = C2 + (size_t)(r0 + t) * NOUT_ + 2112;
    float l[8], mx = -1e30f;
    #pragma unroll
    for (int e = 0; e < 8; ++e) { l[e] = lp[e]; mx = fmaxf(mx, l[e]); }
    float sum = 0.f;
    #pragma unroll
    for (int e = 0; e < 8; ++e) { l[e] = __expf(l[e] - mx); sum += l[e]; }
    float inv = 4.0f / sum;
    #pragma unroll
    for (int e = 0; e < 8; ++e) sm[t][e] = l[e] * inv;
  }
  __syncthreads();

  #pragma unroll
  for (int k = 0; k < 32; ++k) {
    int idx = t + k * 256;
    int er = idx & 63, si = idx >> 6;
    Gt[er][si] = sm[si][er >> 3] * C2[(size_t)(r0 + si) * NOUT_ + 2048 + er];
  }
  const float4* B4 = reinterpret_cast<const float4*>(loB);
  #pragma unroll
  for (int k = 0; k < 16; ++k) {
    int idx = t + k * 256;
    int e = idx >> 9, j = idx & 511;
    int pi = j >> 2, q4 = j & 3;
    float4 v = B4[(size_t)(e * 2048 + 2 * (opbase + pi)) * 2 + q4];
    int half = q4 >> 1, rbase = (q4 & 1) * 4;
    #pragma unroll
    for (int rr = 0; rr < 4; ++rr)
      reinterpret_cast<float*>(&Bs[e * 8 + rbase + rr][pi])[half] = (&v.x)[rr];
  }
  __syncthreads();

  const int pi = t & 127, rh = t >> 7;
  const int ocol = 2 * (opbase + pi);
  for (int rb = 0; rb < 8; ++rb) {
    const int sib = rh * 64 + rb * 8;
    float2 acc[8] = {};
    #pragma unroll 8
    for (int er = 0; er < 64; ++er) {
      float2 b = Bs[er][pi];
      float4 ga = *reinterpret_cast<const float4*>(&Gt[er][sib]);
      float4 gb = *reinterpret_cast<const float4*>(&Gt[er][sib + 4]);
      acc[0].x += ga.x * b.x; acc[0].y += ga.x * b.y;
      acc[1].x += ga.y * b.x; acc[1].y += ga.y * b.y;
      acc[2].x += ga.z * b.x; acc[2].y += ga.z * b.y;
      acc[3].x += ga.w * b.x; acc[3].y += ga.w * b.y;
      acc[4].x += gb.x * b.x; acc[4].y += gb.x * b.y;
      acc[5].x += gb.y * b.x; acc[5].y += gb.y * b.y;
      acc[6].x += gb.z * b.x; acc[6].y += gb.z * b.y;
      acc[7].x += gb.w * b.x; acc[7].y += gb.w * b.y;
    }
    #pragma unroll
    for (int rr = 0; rr < 8; ++rr) {
      size_t row = (size_t)(r0 + sib + rr);
      float2 base = *reinterpret_cast<const float2*>(&C2[row * NOUT_ + ocol]);
      float2 o; o.x = base.x + acc[rr].x; o.y = base.y + acc[rr].y;
      *reinterpret_cast<float2*>(&out[row * 2048 + ocol]) = o;
    }
  }
}

// ---------- V transpose: Vt[hk][d][s] = Vb[s][hk*64+d] ----------
__global__ __launch_bounds__(256) void vt_kernel(const bf16* __restrict__ Vb,
                                                 bf16* __restrict__ Vt) {
  int idx = blockIdx.x * 256 + threadIdx.x;   // NKVH*64*S, s fastest
  int s = idx & 2047, d = (idx >> 11) & 63, hk = idx >> 17;
  Vt[idx] = Vb[(size_t)s * KVD_ + hk * 64 + d];
}

// ---------- MFMA flash attention: 1 wave per (32 q rows, head) ----------
__global__ __launch_bounds__(64, 4) void attn_mfma_kernel(
    const bf16* __restrict__ Q,   // [S][2048], pre-scaled
    const bf16* __restrict__ K,   // [S][512]
    const bf16* __restrict__ Vt,  // [8][64][S]
    bf16* __restrict__ O)         // [S][2048]
{
  __shared__ __align__(16) char p_lds[32 * 144];
  const int lane = threadIdx.x;
  const int fr   = lane & 15;
  const int g    = lane >> 4;
  const int h    = blockIdx.y;
  const int hk   = h >> 2;
  const int qb   = (gridDim.x - 1) - blockIdx.x;   // heavy blocks first
  const int q0   = qb * 32;

  s16x8 qf[2][2];
  #pragma unroll
  for (int i = 0; i < 2; ++i)
    #pragma unroll
    for (int kc = 0; kc < 2; ++kc)
      qf[i][kc] = *reinterpret_cast<const s16x8*>(
          Q + (size_t)(q0 + i * 16 + fr) * 2048 + h * 64 + kc * 32 + g * 8);

  f32x4 acc[4][2] = {};
  float m[2]    = {-1e30f, -1e30f};
  float lsum[2] = {0.f, 0.f};

  const bf16* Kh  = K  + hk * 64;
  const bf16* Vth = Vt + (size_t)hk * 64 * S_;

  const int ntiles = (q0 + 32 + 63) >> 6;
  const int nomask = (q0 + 1) >> 6;

  for (int t = 0; t < ntiles; ++t) {
    const int k0 = t * 64;

    f32x4 st[4][2] = {};
    __builtin_amdgcn_s_setprio(1);
    #pragma unroll
    for (int kc = 0; kc < 2; ++kc)
      #pragma unroll
      for (int kt = 0; kt < 4; ++kt) {
        s16x8 kf = *reinterpret_cast<const s16x8*>(
            Kh + (size_t)(k0 + kt * 16 + fr) * KVD_ + kc * 32 + g * 8);
        #pragma unroll
        for (int i = 0; i < 2; ++i)
          st[kt][i] = __builtin_amdgcn_mfma_f32_16x16x32_bf16(kf, qf[i][kc], st[kt][i], 0, 0, 0);
      }
    __builtin_amdgcn_s_setprio(0);

    if (t >= nomask) {
      #pragma unroll
      for (int kt = 0; kt < 4; ++kt)
        #pragma unroll
        for (int i = 0; i < 2; ++i)
          #pragma unroll
          for (int r = 0; r < 4; ++r) {
            int key = k0 + kt * 16 + g * 4 + r;
            int q   = q0 + i * 16 + fr;
            if (key > q) st[kt][i][r] = -1e30f;
          }
    }

    #pragma unroll
    for (int i = 0; i < 2; ++i) {
      float tm = -1e30f;
      #pragma unroll
      for (int kt = 0; kt < 4; ++kt)
        #pragma unroll
        for (int r = 0; r < 4; ++r)
          tm = fmaxf(tm, st[kt][i][r]);
      tm = fmaxf(tm, __shfl_xor(tm, 16));
      tm = fmaxf(tm, __shfl_xor(tm, 32));
      float newm = fmaxf(m[i], tm);
      float rs = __expf(m[i] - newm);
      m[i] = newm;
      lsum[i] *= rs;
      #pragma unroll
      for (int dt = 0; dt < 4; ++dt)
        #pragma unroll
        for (int r = 0; r < 4; ++r)
          acc[dt][i][r] *= rs;
      #pragma unroll
      for (int kt = 0; kt < 4; ++kt) {
        float p0 = __expf(st[kt][i][0] - newm);
        float p1 = __expf(st[kt][i][1] - newm);
        float p2 = __expf(st[kt][i][2] - newm);
        float p3 = __expf(st[kt][i][3] - newm);
        lsum[i] += (p0 + p1) + (p2 + p3);
        unsigned w0 = (unsigned)f2bf_bits(p0) | ((unsigned)f2bf_bits(p1) << 16);
        unsigned w1 = (unsigned)f2bf_bits(p2) | ((unsigned)f2bf_bits(p3) << 16);
        char* base = p_lds + (i * 16 + fr) * 144 + (kt * 16 + g * 4) * 2;
        *reinterpret_cast<unsigned*>(base)     = w0;
        *reinterpret_cast<unsigned*>(base + 4) = w1;
      }
    }

    __builtin_amdgcn_s_setprio(1);
    #pragma unroll
    for (int kc = 0; kc < 2; ++kc) {
      s16x8 pf[2];
      #pragma unroll
      for (int i = 0; i < 2; ++i)
        pf[i] = *reinterpret_cast<const s16x8*>(
            p_lds + (i * 16 + fr) * 144 + (kc * 32 + g * 8) * 2);
      #pragma unroll
      for (int dt = 0; dt < 4; ++dt) {
        s16x8 vf = *reinterpret_cast<const s16x8*>(
            Vth + (size_t)(dt * 16 + fr) * S_ + k0 + kc * 32 + g * 8);
        #pragma unroll
        for (int i = 0; i < 2; ++i)
          acc[dt][i] = __builtin_amdgcn_mfma_f32_16x16x32_bf16(vf, pf[i], acc[dt][i], 0, 0, 0);
      }
    }
    __builtin_amdgcn_s_setprio(0);
  }

  #pragma unroll
  for (int i = 0; i < 2; ++i) {
    lsum[i] += __shfl_xor(lsum[i], 16);
    lsum[i] += __shfl_xor(lsum[i], 32);
  }
  float inv0 = 1.f / lsum[0], inv1 = 1.f / lsum[1];
  #pragma unroll
  for (int i = 0; i < 2; ++i) {
    float inv = i ? inv1 : inv0;
    #pragma unroll
    for (int dt = 0; dt < 4; ++dt)
      #pragma unroll
      for (int r2 = 0; r2 < 2; ++r2) {
        unsigned o = (unsigned)f2bf_bits(acc[dt][i][2 * r2] * inv)
                   | ((unsigned)f2bf_bits(acc[dt][i][2 * r2 + 1] * inv) << 16);
        size_t off = (size_t)(q0 + i * 16 + fr) * 2048 + h * 64 + dt * 16 + g * 4 + 2 * r2;
        *reinterpret_cast<unsigned*>(O + off) = o;
      }
  }
}

extern "C" void kernel_launch(void* const* d_in, const int* in_sizes, int n_in,
                              void* d_out, int out_size, void* d_ws, size_t ws_size,
                              hipStream_t stream) {
  const float* x   = (const float*)d_in[0];
  const float* fc  = (const float*)d_in[3];
  const float* fs  = (const float*)d_in[4];
  const float* wq  = (const float*)d_in[5];
  const float* wk  = (const float*)d_in[6];
  const float* wv  = (const float*)d_in[7];
  const float* wo  = (const float*)d_in[8];
  const float* lqR = (const float*)d_in[9];
  const float* lqA = (const float*)d_in[10];
  const float* lqB = (const float*)d_in[11];
  const float* lkR = (const float*)d_in[12];
  const float* lkA = (const float*)d_in[13];
  const float* lkB = (const float*)d_in[14];
  const float* lvR = (const float*)d_in[15];
  const float* lvA = (const float*)d_in[16];
  const float* lvB = (const float*)d_in[17];
  const float* loR = (const float*)d_in[18];
  const float* loA = (const float*)d_in[19];
  const float* loB = (const float*)d_in[20];
  float* out = (float*)d_out;
  char* ws = (char*)d_ws;

  if (ws_size < 58000000u) return;

  bf16* xb   = (bf16*)(ws + 0);            // 8 MB; aliased as AOb after gemm1
  bf16* Wqkv = (bf16*)(ws + 8388608);      // 13.47 MB; aliased as Wout after gemm1
  bf16* Qb   = (bf16*)(ws + 21856256);     // 8 MB
  bf16* Kb   = (bf16*)(ws + 30244864);     // 2 MB
  bf16* Vb   = (bf16*)(ws + 32342016);     // 2 MB
  bf16* Vt   = (bf16*)(ws + 34439168);     // 2 MB
  bf16* C1   = (bf16*)(ws + 36536320);     // 13.47 MB (dead after epilogue)
  float* C2  = (float*)(ws + 21856256);    // 17.37 MB, overlays Qb..C1-head (all dead)
  bf16* AOb  = xb;
  bf16* Wout = Wqkv;

  cast4_kernel<<<dim3(S_ * D_ / 4 / 256), dim3(256), 0, stream>>>(x, xb, S_ * D_ / 4);
  pack_qkv_kernel<<<dim3(NQKV_), dim3(256), 0, stream>>>(wq, wk, wv, lqA, lkA, lvA,
                                                         lqR, lkR, lvR, Wqkv);
  gemm_bt_kernel<bf16><<<dim3((NQKV_ + 127) / 128, S_ / 128), dim3(256), 0, stream>>>(
      xb, Wqkv, C1, S_, NQKV_, D_);
  qkv_epilogue2_kernel<<<dim3(12, 16), dim3(256), 0, stream>>>(C1, fc, fs, lqB, lkB, lvB,
                                                               Qb, Kb, Vb);
  vt_kernel<<<dim3(NKVH_ * 64 * S_ / 256), dim3(256), 0, stream>>>(Vb, Vt);
  attn_mfma_kernel<<<dim3(S_ / 32, NH_), dim3(64), 0, stream>>>(Qb, Kb, Vt, AOb);
  pack_out_kernel<<<dim3(NOUT_), dim3(256), 0, stream>>>(wo, loA, loR, Wout);
  gemm_bt_kernel<float><<<dim3((NOUT_ + 127) / 128, S_ / 128), dim3(256), 0, stream>>>(
      AOb, Wout, C2, S_, NOUT_, D_);
  out_epilogue2_kernel<<<dim3(8, 16), dim3(256), 0, stream>>>(C2, loB, out);
}

// Round 6
// 274.351 us; speedup vs baseline: 5.8950x; 1.3055x over previous
//
#include <hip/hip_runtime.h>
#include <hip/hip_bf16.h>

static constexpr int S_    = 2048;
static constexpr int D_    = 2048;
static constexpr int NH_   = 32;
static constexpr int NKVH_ = 8;
static constexpr int HD_   = 64;
static constexpr int KVD_  = NKVH_ * HD_;   // 512
static constexpr int NQKV_ = 3288;          // 2048 q + 512 k + 512 v + 192 H + 24 logits
static constexpr int NOUT_ = 2120;          // 2048 o + 64 H + 8 logits

using bf16 = __hip_bfloat16;
typedef __attribute__((ext_vector_type(4))) float f32x4;
typedef __attribute__((ext_vector_type(8))) short s16x8;

__device__ inline unsigned short f2bf_bits(float f) {
  bf16 h = __float2bfloat16(f);
  union { bf16 b; unsigned short u; } cv; cv.b = h; return cv.u;
}
__device__ inline float bfbits2f(unsigned short u) {
  union { unsigned u32; float f; } cv; cv.u32 = (unsigned)u << 16; return cv.f;
}
__device__ inline float fexp2(float x) {
#if __has_builtin(__builtin_amdgcn_exp2f)
  return __builtin_amdgcn_exp2f(x);
#else
  return __expf(x * 0.6931471805599453f);
#endif
}

// ---------- f32 -> bf16 cast ----------
__global__ __launch_bounds__(256) void cast4_kernel(const float* __restrict__ in,
                                                    bf16* __restrict__ out, int n4) {
  int i = blockIdx.x * 256 + threadIdx.x;
  if (i >= n4) return;
  float4 v = reinterpret_cast<const float4*>(in)[i];
  ushort4 o;
  o.x = f2bf_bits(v.x); o.y = f2bf_bits(v.y); o.z = f2bf_bits(v.z); o.w = f2bf_bits(v.w);
  reinterpret_cast<ushort4*>(out)[i] = o;
}

// ---------- weight packing (concat rows, f32 -> bf16), K = 2048 ----------
__global__ __launch_bounds__(256) void pack_qkv_kernel(
    const float* __restrict__ wq, const float* __restrict__ wk, const float* __restrict__ wv,
    const float* __restrict__ lqA, const float* __restrict__ lkA, const float* __restrict__ lvA,
    const float* __restrict__ lqR, const float* __restrict__ lkR, const float* __restrict__ lvR,
    bf16* __restrict__ Wp) {
  int r = blockIdx.x;
  const float* src;
  if      (r < 2048) src = wq  + (size_t)r * 2048;
  else if (r < 2560) src = wk  + (size_t)(r - 2048) * 2048;
  else if (r < 3072) src = wv  + (size_t)(r - 2560) * 2048;
  else if (r < 3136) src = lqA + (size_t)(r - 3072) * 2048;
  else if (r < 3200) src = lkA + (size_t)(r - 3136) * 2048;
  else if (r < 3264) src = lvA + (size_t)(r - 3200) * 2048;
  else if (r < 3272) src = lqR + (size_t)(r - 3264) * 2048;
  else if (r < 3280) src = lkR + (size_t)(r - 3272) * 2048;
  else               src = lvR + (size_t)(r - 3280) * 2048;
  bf16* dst = Wp + (size_t)r * 2048;
  for (int c = threadIdx.x; c < 512; c += 256) {
    float4 v = reinterpret_cast<const float4*>(src)[c];
    ushort4 o;
    o.x = f2bf_bits(v.x); o.y = f2bf_bits(v.y); o.z = f2bf_bits(v.z); o.w = f2bf_bits(v.w);
    reinterpret_cast<ushort4*>(dst)[c] = o;
  }
}

__global__ __launch_bounds__(256) void pack_out_kernel(
    const float* __restrict__ wo, const float* __restrict__ loA,
    const float* __restrict__ loR, bf16* __restrict__ Wp) {
  int r = blockIdx.x;
  const float* src;
  if      (r < 2048) src = wo  + (size_t)r * 2048;
  else if (r < 2112) src = loA + (size_t)(r - 2048) * 2048;
  else               src = loR + (size_t)(r - 2112) * 2048;
  bf16* dst = Wp + (size_t)r * 2048;
  for (int c = threadIdx.x; c < 512; c += 256) {
    float4 v = reinterpret_cast<const float4*>(src)[c];
    ushort4 o;
    o.x = f2bf_bits(v.x); o.y = f2bf_bits(v.y); o.z = f2bf_bits(v.z); o.w = f2bf_bits(v.w);
    reinterpret_cast<ushort4*>(dst)[c] = o;
  }
}

// ---------- bf16 MFMA GEMM: C[M][N] = X[M][K] @ W[N][K]^T (m97 structure) ----------
__device__ inline void gld_lds16(const void* g, void* l) {
  __builtin_amdgcn_global_load_lds((const __attribute__((address_space(1))) void*)g,
                                   (__attribute__((address_space(3))) void*)l, 16, 0, 0);
}

template <typename OT>
__global__ __launch_bounds__(256) void gemm_bt_kernel(
    const bf16* __restrict__ X, const bf16* __restrict__ W,
    OT* __restrict__ C, int M, int N, int K)
{
  __shared__ __align__(16) bf16 As[128 * 32];
  __shared__ __align__(16) bf16 Bs[128 * 32];
  const int tid = threadIdx.x;
  const int lane = tid & 63;
  const int wid = tid >> 6;
  const int m0 = blockIdx.y * 128;
  const int n0 = blockIdx.x * 128;
  const int wm = (wid >> 1) * 64;
  const int wn = (wid & 1) * 64;

  f32x4 acc[4][4] = {};
  const int kg = (lane >> 4) * 8;
  const int fr = lane & 15;

  for (int kt = 0; kt < K; kt += 32) {
    #pragma unroll
    for (int c = 0; c < 2; ++c) {
      int o  = c * 4096 + tid * 16;
      int r  = o >> 6;
      int ke = (o & 63) >> 1;
      const bf16* srcA = X + (size_t)(m0 + r) * K + kt + ke;
      gld_lds16(srcA, (char*)As + o);
      int wr = n0 + r; if (wr > N - 1) wr = N - 1;
      const bf16* srcB = W + (size_t)wr * K + kt + ke;
      gld_lds16(srcB, (char*)Bs + o);
    }
    __syncthreads();
    s16x8 af[4], bfr[4];
    #pragma unroll
    for (int i = 0; i < 4; ++i) {
      af[i]  = *reinterpret_cast<const s16x8*>(&As[(wm + i * 16 + fr) * 32 + kg]);
      bfr[i] = *reinterpret_cast<const s16x8*>(&Bs[(wn + i * 16 + fr) * 32 + kg]);
    }
    #pragma unroll
    for (int i = 0; i < 4; ++i)
      #pragma unroll
      for (int j = 0; j < 4; ++j)
        acc[i][j] = __builtin_amdgcn_mfma_f32_16x16x32_bf16(af[i], bfr[j], acc[i][j], 0, 0, 0);
    __syncthreads();
  }

  const int cr = (lane >> 4) * 4;
  const int cc = lane & 15;
  #pragma unroll
  for (int i = 0; i < 4; ++i)
    #pragma unroll
    for (int j = 0; j < 4; ++j) {
      int gn = n0 + wn + j * 16 + cc;
      if (gn >= N) continue;
      #pragma unroll
      for (int r = 0; r < 4; ++r) {
        int gm = m0 + wm + i * 16 + cr + r;
        if constexpr (__is_same(OT, bf16))
          C[(size_t)gm * N + gn] = __float2bfloat16(acc[i][j][r]);
        else
          C[(size_t)gm * N + gn] = acc[i][j][r];
      }
    }
}

// ---------- QKV epilogue: 2-D tiled, B staged in LDS ----------
// Q is pre-scaled by 0.125 * log2(e) so attention can use exp2 directly.
__global__ __launch_bounds__(256) void qkv_epilogue2_kernel(
    const bf16* __restrict__ C1, const float* __restrict__ fc, const float* __restrict__ fs,
    const float* __restrict__ lqB, const float* __restrict__ lkB, const float* __restrict__ lvB,
    bf16* __restrict__ Qb, bf16* __restrict__ Kb, bf16* __restrict__ Vb)
{
  __shared__ float sm[128][8];
  __shared__ __align__(16) float Gt[64][132];   // [er][si], pitch 132 for f4 align
  __shared__ __align__(16) float2 Bs[64][128];  // [er][pair] = {col0, col1}
  const int bx = blockIdx.x;
  const int r0 = blockIdx.y * 128;
  const int t  = threadIdx.x;
  int seg, OUT, opbase; const float* Bp;
  if (bx < 8)       { seg = 0; OUT = 2048; opbase = bx * 128;        Bp = lqB; }
  else if (bx < 10) { seg = 1; OUT = 512;  opbase = (bx - 8) * 128;  Bp = lkB; }
  else              { seg = 2; OUT = 512;  opbase = (bx - 10) * 128; Bp = lvB; }

  const unsigned short* C1u = reinterpret_cast<const unsigned short*>(C1);

  if (t < 128) {
    const unsigned short* lp = C1u + (size_t)(r0 + t) * NQKV_ + 3264 + seg * 8;
    float l[8], mx = -1e30f;
    #pragma unroll
    for (int e = 0; e < 8; ++e) { l[e] = bfbits2f(lp[e]); mx = fmaxf(mx, l[e]); }
    float sum = 0.f;
    #pragma unroll
    for (int e = 0; e < 8; ++e) { l[e] = __expf(l[e] - mx); sum += l[e]; }
    float inv = 4.0f / sum;
    #pragma unroll
    for (int e = 0; e < 8; ++e) sm[t][e] = l[e] * inv;
  }
  __syncthreads();

  #pragma unroll
  for (int k = 0; k < 32; ++k) {
    int idx = t + k * 256;
    int er = idx & 63, si = idx >> 6;
    float h = bfbits2f(C1u[(size_t)(r0 + si) * NQKV_ + 3072 + seg * 64 + er]);
    Gt[er][si] = sm[si][er >> 3] * h;
  }
  const float4* B4 = reinterpret_cast<const float4*>(Bp);
  #pragma unroll
  for (int k = 0; k < 16; ++k) {
    int idx = t + k * 256;
    int e = idx >> 9, j = idx & 511;
    int pi = j >> 2, q4 = j & 3;
    float4 v = B4[(size_t)(e * OUT + 2 * (opbase + pi)) * 2 + q4];
    int half = q4 >> 1, rbase = (q4 & 1) * 4;
    #pragma unroll
    for (int rr = 0; rr < 4; ++rr)
      reinterpret_cast<float*>(&Bs[e * 8 + rbase + rr][pi])[half] = (&v.x)[rr];
  }
  __syncthreads();

  const int pi = t & 127, rh = t >> 7;
  const int colC1 = 2 * (128 * bx + pi);
  const int ocol = 2 * (opbase + pi);
  const int hdp = pi & 31;
  for (int rb = 0; rb < 8; ++rb) {
    const int sib = rh * 64 + rb * 8;
    float2 acc[8] = {};
    #pragma unroll 8
    for (int er = 0; er < 64; ++er) {
      float2 b = Bs[er][pi];
      float4 ga = *reinterpret_cast<const float4*>(&Gt[er][sib]);
      float4 gb = *reinterpret_cast<const float4*>(&Gt[er][sib + 4]);
      acc[0].x += ga.x * b.x; acc[0].y += ga.x * b.y;
      acc[1].x += ga.y * b.x; acc[1].y += ga.y * b.y;
      acc[2].x += ga.z * b.x; acc[2].y += ga.z * b.y;
      acc[3].x += ga.w * b.x; acc[3].y += ga.w * b.y;
      acc[4].x += gb.x * b.x; acc[4].y += gb.x * b.y;
      acc[5].x += gb.y * b.x; acc[5].y += gb.y * b.y;
      acc[6].x += gb.z * b.x; acc[6].y += gb.z * b.y;
      acc[7].x += gb.w * b.x; acc[7].y += gb.w * b.y;
    }
    #pragma unroll
    for (int rr = 0; rr < 8; ++rr) {
      size_t row = (size_t)(r0 + sib + rr);
      unsigned base = *reinterpret_cast<const unsigned*>(&C1u[row * NQKV_ + colC1]);
      float v0 = bfbits2f((unsigned short)(base & 0xffff)) + acc[rr].x;
      float v1 = bfbits2f((unsigned short)(base >> 16))    + acc[rr].y;
      if (seg == 0) {
        float c = fc[row * 32 + hdp], sn = fs[row * 32 + hdp];
        unsigned o = (unsigned)f2bf_bits((v0 * c - v1 * sn) * 0.18033688f)
                   | ((unsigned)f2bf_bits((v0 * sn + v1 * c) * 0.18033688f) << 16);
        *reinterpret_cast<unsigned*>(&Qb[row * 2048 + ocol]) = o;
      } else if (seg == 1) {
        float c = fc[row * 32 + hdp], sn = fs[row * 32 + hdp];
        unsigned o = (unsigned)f2bf_bits(v0 * c - v1 * sn)
                   | ((unsigned)f2bf_bits(v0 * sn + v1 * c) << 16);
        *reinterpret_cast<unsigned*>(&Kb[row * 512 + ocol]) = o;
      } else {
        unsigned o = (unsigned)f2bf_bits(v0) | ((unsigned)f2bf_bits(v1) << 16);
        *reinterpret_cast<unsigned*>(&Vb[row * 512 + ocol]) = o;
      }
    }
  }
}

// ---------- output epilogue: 2-D tiled, loB staged in LDS ----------
__global__ __launch_bounds__(256) void out_epilogue2_kernel(
    const float* __restrict__ C2, const float* __restrict__ loB, float* __restrict__ out)
{
  __shared__ float sm[128][8];
  __shared__ __align__(16) float Gt[64][132];
  __shared__ __align__(16) float2 Bs[64][128];
  const int bx = blockIdx.x;
  const int r0 = blockIdx.y * 128;
  const int t  = threadIdx.x;
  const int opbase = bx * 128;

  if (t < 128) {
    const float* lp = C2 + (size_t)(r0 + t) * NOUT_ + 2112;
    float l[8], mx = -1e30f;
    #pragma unroll
    for (int e = 0; e < 8; ++e) { l[e] = lp[e]; mx = fmaxf(mx, l[e]); }
    float sum = 0.f;
    #pragma unroll
    for (int e = 0; e < 8; ++e) { l[e] = __expf(l[e] - mx); sum += l[e]; }
    float inv = 4.0f / sum;
    #pragma unroll
    for (int e = 0; e < 8; ++e) sm[t][e] = l[e] * inv;
  }
  __syncthreads();

  #pragma unroll
  for (int k = 0; k < 32; ++k) {
    int idx = t + k * 256;
    int er = idx & 63, si = idx >> 6;
    Gt[er][si] = sm[si][er >> 3] * C2[(size_t)(r0 + si) * NOUT_ + 2048 + er];
  }
  const float4* B4 = reinterpret_cast<const float4*>(loB);
  #pragma unroll
  for (int k = 0; k < 16; ++k) {
    int idx = t + k * 256;
    int e = idx >> 9, j = idx & 511;
    int pi = j >> 2, q4 = j & 3;
    float4 v = B4[(size_t)(e * 2048 + 2 * (opbase + pi)) * 2 + q4];
    int half = q4 >> 1, rbase = (q4 & 1) * 4;
    #pragma unroll
    for (int rr = 0; rr < 4; ++rr)
      reinterpret_cast<float*>(&Bs[e * 8 + rbase + rr][pi])[half] = (&v.x)[rr];
  }
  __syncthreads();

  const int pi = t & 127, rh = t >> 7;
  const int ocol = 2 * (opbase + pi);
  for (int rb = 0; rb < 8; ++rb) {
    const int sib = rh * 64 + rb * 8;
    float2 acc[8] = {};
    #pragma unroll 8
    for (int er = 0; er < 64; ++er) {
      float2 b = Bs[er][pi];
      float4 ga = *reinterpret_cast<const float4*>(&Gt[er][sib]);
      float4 gb = *reinterpret_cast<const float4*>(&Gt[er][sib + 4]);
      acc[0].x += ga.x * b.x; acc[0].y += ga.x * b.y;
      acc[1].x += ga.y * b.x; acc[1].y += ga.y * b.y;
      acc[2].x += ga.z * b.x; acc[2].y += ga.z * b.y;
      acc[3].x += ga.w * b.x; acc[3].y += ga.w * b.y;
      acc[4].x += gb.x * b.x; acc[4].y += gb.x * b.y;
      acc[5].x += gb.y * b.x; acc[5].y += gb.y * b.y;
      acc[6].x += gb.z * b.x; acc[6].y += gb.z * b.y;
      acc[7].x += gb.w * b.x; acc[7].y += gb.w * b.y;
    }
    #pragma unroll
    for (int rr = 0; rr < 8; ++rr) {
      size_t row = (size_t)(r0 + sib + rr);
      float2 base = *reinterpret_cast<const float2*>(&C2[row * NOUT_ + ocol]);
      float2 o; o.x = base.x + acc[rr].x; o.y = base.y + acc[rr].y;
      *reinterpret_cast<float2*>(&out[row * 2048 + ocol]) = o;
    }
  }
}

// ---------- V transpose (LDS-tiled): Vt[hk][d][s] = Vb[s][hk*64+d] ----------
__global__ __launch_bounds__(256) void vt2_kernel(const unsigned short* __restrict__ Vb,
                                                  unsigned short* __restrict__ Vt) {
  __shared__ unsigned short tile[64][72];
  const int hk = blockIdx.x >> 5;
  const int s0 = (blockIdx.x & 31) * 64;
  const int t  = threadIdx.x;
  // load: 512 idx x 8 shorts = 64 rows x 64 d
  #pragma unroll
  for (int r = 0; r < 2; ++r) {
    int idx = r * 256 + t;
    int row = idx >> 3, cc = idx & 7;
    *reinterpret_cast<s16x8*>(&tile[row][cc * 8]) =
        *reinterpret_cast<const s16x8*>(&Vb[(size_t)(s0 + row) * KVD_ + hk * 64 + cc * 8]);
  }
  __syncthreads();
  // store: 256 idx x 16 shorts = 64 d x 64 s  (single pass — d = t>>2 in [0,64))
  {
    int d = t >> 2, seg = t & 3;
    s16x8 o0;
    #pragma unroll
    for (int j = 0; j < 8; ++j) o0[j] = (short)tile[seg * 16 + j][d];
    s16x8 o1;
    #pragma unroll
    for (int j = 0; j < 8; ++j) o1[j] = (short)tile[seg * 16 + 8 + j][d];
    unsigned short* dst = Vt + ((size_t)hk * 64 + d) * S_ + s0 + seg * 16;
    *reinterpret_cast<s16x8*>(dst)     = o0;
    *reinterpret_cast<s16x8*>(dst + 8) = o1;
  }
}

// ---------- MFMA flash attention v2: 4-wave WG, LDS-staged K/V ----------
// WG = (head, 128 q rows); wave w owns rows q0 = c*128 + w*32 .. +31.
// K/V tiles (64 keys) double-buffered in LDS, layout [kc][64 rows][32 halves]
// so frag ds_reads are contiguous 1KB per wave (conflict-free).
__global__ __launch_bounds__(256, 2) void attn_mfma2_kernel(
    const bf16* __restrict__ Q,   // [S][2048], pre-scaled by 0.125*log2(e)
    const bf16* __restrict__ K,   // [S][512]
    const bf16* __restrict__ Vt,  // [8][64][S]
    bf16* __restrict__ O)         // [S][2048]
{
  __shared__ __align__(16) bf16 Klds[2][2][64][32];
  __shared__ __align__(16) bf16 Vlds[2][2][64][32];
  __shared__ __align__(16) char p_all[4][32 * 144];
  const int tid  = threadIdx.x;
  const int lane = tid & 63;
  const int w    = tid >> 6;
  const int fr   = lane & 15;
  const int g    = lane >> 4;
  const int bx   = blockIdx.x;
  const int c    = 15 - (bx >> 5);            // heavy chunks first
  const int h    = bx & 31;
  const int hk   = h >> 2;
  const int q0   = c * 128 + w * 32;
  char* p_lds = p_all[w];
  const bf16* Kh  = K  + hk * 64;
  const bf16* Vth = Vt + (size_t)hk * 64 * S_;

  const int nt_wg  = 2 * c + 2;               // tiles the WG stages
  const int nt_me  = (q0 + 32 + 63) >> 6;     // tiles this wave computes
  const int nomask = (q0 + 1) >> 6;

  s16x8 qf[2][2];
  #pragma unroll
  for (int i = 0; i < 2; ++i)
    #pragma unroll
    for (int kc = 0; kc < 2; ++kc)
      qf[i][kc] = *reinterpret_cast<const s16x8*>(
          Q + (size_t)(q0 + i * 16 + fr) * 2048 + h * 64 + kc * 32 + g * 8);

  f32x4 acc[4][2] = {};
  float m[2]    = {-1e30f, -1e30f};
  float lsum[2] = {0.f, 0.f};

  // prologue: stage tile 0 into buf 0
  #pragma unroll
  for (int r = 0; r < 2; ++r) {
    int cidx = w * 128 + r * 64 + lane;
    int kc = cidx >> 8, row = (cidx >> 2) & 63, gg = cidx & 3;
    gld_lds16(Kh  + (size_t)row * KVD_ + kc * 32 + gg * 8, (char*)Klds[0] + cidx * 16);
    gld_lds16(Vth + (size_t)row * S_   + kc * 32 + gg * 8, (char*)Vlds[0] + cidx * 16);
  }
  __syncthreads();

  int cur = 0;
  for (int t = 0; t < nt_wg; ++t) {
    const int k0 = t * 64;
    if (t + 1 < nt_wg) {
      const int k0n = k0 + 64;
      #pragma unroll
      for (int r = 0; r < 2; ++r) {
        int cidx = w * 128 + r * 64 + lane;
        int kc = cidx >> 8, row = (cidx >> 2) & 63, gg = cidx & 3;
        gld_lds16(Kh  + (size_t)(k0n + row) * KVD_ + kc * 32 + gg * 8,
                  (char*)Klds[cur ^ 1] + cidx * 16);
        gld_lds16(Vth + (size_t)row * S_ + k0n + kc * 32 + gg * 8,
                  (char*)Vlds[cur ^ 1] + cidx * 16);
      }
    }
    if (t < nt_me) {
      // ---- QK^T (swapped): st[kt][i] = S[key=k0+kt*16+g*4+r][q=q0+i*16+fr]
      f32x4 st[4][2] = {};
      __builtin_amdgcn_s_setprio(1);
      #pragma unroll
      for (int kc = 0; kc < 2; ++kc)
        #pragma unroll
        for (int kt = 0; kt < 4; ++kt) {
          s16x8 kf = *reinterpret_cast<const s16x8*>(&Klds[cur][kc][kt * 16 + fr][g * 8]);
          #pragma unroll
          for (int i = 0; i < 2; ++i)
            st[kt][i] = __builtin_amdgcn_mfma_f32_16x16x32_bf16(kf, qf[i][kc], st[kt][i], 0, 0, 0);
        }
      __builtin_amdgcn_s_setprio(0);

      if (t >= nomask) {
        #pragma unroll
        for (int kt = 0; kt < 4; ++kt)
          #pragma unroll
          for (int i = 0; i < 2; ++i)
            #pragma unroll
            for (int r = 0; r < 4; ++r) {
              int key = k0 + kt * 16 + g * 4 + r;
              int q   = q0 + i * 16 + fr;
              if (key > q) st[kt][i][r] = -1e30f;
            }
      }

      // ---- online softmax (exp2 domain, defer-max THR=8)
      #pragma unroll
      for (int i = 0; i < 2; ++i) {
        float tm = -1e30f;
        #pragma unroll
        for (int kt = 0; kt < 4; ++kt)
          #pragma unroll
          for (int r = 0; r < 4; ++r)
            tm = fmaxf(tm, st[kt][i][r]);
        tm = fmaxf(tm, __shfl_xor(tm, 16));
        tm = fmaxf(tm, __shfl_xor(tm, 32));
        float newm = m[i];
        if (!__all(tm <= m[i] + 8.f)) {
          newm = fmaxf(m[i], tm);
          float rs = fexp2(m[i] - newm);
          lsum[i] *= rs;
          #pragma unroll
          for (int dt = 0; dt < 4; ++dt)
            #pragma unroll
            for (int r = 0; r < 4; ++r)
              acc[dt][i][r] *= rs;
          m[i] = newm;
        }
        #pragma unroll
        for (int kt = 0; kt < 4; ++kt) {
          float p0 = fexp2(st[kt][i][0] - newm);
          float p1 = fexp2(st[kt][i][1] - newm);
          float p2 = fexp2(st[kt][i][2] - newm);
          float p3 = fexp2(st[kt][i][3] - newm);
          lsum[i] += (p0 + p1) + (p2 + p3);
          uint2 pw;
          pw.x = (unsigned)f2bf_bits(p0) | ((unsigned)f2bf_bits(p1) << 16);
          pw.y = (unsigned)f2bf_bits(p2) | ((unsigned)f2bf_bits(p3) << 16);
          *reinterpret_cast<uint2*>(p_lds + (i * 16 + fr) * 144 + (kt * 16 + g * 4) * 2) = pw;
        }
      }

      // ---- PV (swapped): acc[dt][i] += Vt-frag x P-frag
      __builtin_amdgcn_s_setprio(1);
      #pragma unroll
      for (int kc = 0; kc < 2; ++kc) {
        s16x8 pf[2];
        #pragma unroll
        for (int i = 0; i < 2; ++i)
          pf[i] = *reinterpret_cast<const s16x8*>(
              p_lds + (i * 16 + fr) * 144 + (kc * 32 + g * 8) * 2);
        #pragma unroll
        for (int dt = 0; dt < 4; ++dt) {
          s16x8 vf = *reinterpret_cast<const s16x8*>(&Vlds[cur][kc][dt * 16 + fr][g * 8]);
          #pragma unroll
          for (int i = 0; i < 2; ++i)
            acc[dt][i] = __builtin_amdgcn_mfma_f32_16x16x32_bf16(vf, pf[i], acc[dt][i], 0, 0, 0);
        }
      }
      __builtin_amdgcn_s_setprio(0);
    }
    __syncthreads();
    cur ^= 1;
  }

  // ---- epilogue
  #pragma unroll
  for (int i = 0; i < 2; ++i) {
    lsum[i] += __shfl_xor(lsum[i], 16);
    lsum[i] += __shfl_xor(lsum[i], 32);
  }
  float inv0 = 1.f / lsum[0], inv1 = 1.f / lsum[1];
  #pragma unroll
  for (int i = 0; i < 2; ++i) {
    float inv = i ? inv1 : inv0;
    #pragma unroll
    for (int dt = 0; dt < 4; ++dt)
      #pragma unroll
      for (int r2 = 0; r2 < 2; ++r2) {
        unsigned o = (unsigned)f2bf_bits(acc[dt][i][2 * r2] * inv)
                   | ((unsigned)f2bf_bits(acc[dt][i][2 * r2 + 1] * inv) << 16);
        size_t off = (size_t)(q0 + i * 16 + fr) * 2048 + h * 64 + dt * 16 + g * 4 + 2 * r2;
        *reinterpret_cast<unsigned*>(O + off) = o;
      }
  }
}

extern "C" void kernel_launch(void* const* d_in, const int* in_sizes, int n_in,
                              void* d_out, int out_size, void* d_ws, size_t ws_size,
                              hipStream_t stream) {
  const float* x   = (const float*)d_in[0];
  const float* fc  = (const float*)d_in[3];
  const float* fs  = (const float*)d_in[4];
  const float* wq  = (const float*)d_in[5];
  const float* wk  = (const float*)d_in[6];
  const float* wv  = (const float*)d_in[7];
  const float* wo  = (const float*)d_in[8];
  const float* lqR = (const float*)d_in[9];
  const float* lqA = (const float*)d_in[10];
  const float* lqB = (const float*)d_in[11];
  const float* lkR = (const float*)d_in[12];
  const float* lkA = (const float*)d_in[13];
  const float* lkB = (const float*)d_in[14];
  const float* lvR = (const float*)d_in[15];
  const float* lvA = (const float*)d_in[16];
  const float* lvB = (const float*)d_in[17];
  const float* loR = (const float*)d_in[18];
  const float* loA = (const float*)d_in[19];
  const float* loB = (const float*)d_in[20];
  float* out = (float*)d_out;
  char* ws = (char*)d_ws;

  if (ws_size < 58000000u) return;

  bf16* xb   = (bf16*)(ws + 0);            // 8 MB; aliased as AOb after gemm1
  bf16* Wqkv = (bf16*)(ws + 8388608);      // 13.47 MB; aliased as Wout after gemm1
  bf16* Qb   = (bf16*)(ws + 21856256);     // 8 MB
  bf16* Kb   = (bf16*)(ws + 30244864);     // 2 MB
  bf16* Vb   = (bf16*)(ws + 32342016);     // 2 MB
  bf16* Vt   = (bf16*)(ws + 34439168);     // 2 MB
  bf16* C1   = (bf16*)(ws + 36536320);     // 13.47 MB (dead after epilogue)
  float* C2  = (float*)(ws + 21856256);    // 17.37 MB, overlays Qb..C1-head (all dead)
  bf16* AOb  = xb;
  bf16* Wout = Wqkv;

  cast4_kernel<<<dim3(S_ * D_ / 4 / 256), dim3(256), 0, stream>>>(x, xb, S_ * D_ / 4);
  pack_qkv_kernel<<<dim3(NQKV_), dim3(256), 0, stream>>>(wq, wk, wv, lqA, lkA, lvA,
                                                         lqR, lkR, lvR, Wqkv);
  gemm_bt_kernel<bf16><<<dim3((NQKV_ + 127) / 128, S_ / 128), dim3(256), 0, stream>>>(
      xb, Wqkv, C1, S_, NQKV_, D_);
  qkv_epilogue2_kernel<<<dim3(12, 16), dim3(256), 0, stream>>>(C1, fc, fs, lqB, lkB, lvB,
                                                               Qb, Kb, Vb);
  vt2_kernel<<<dim3(256), dim3(256), 0, stream>>>((const unsigned short*)Vb,
                                                  (unsigned short*)Vt);
  attn_mfma2_kernel<<<dim3(512), dim3(256), 0, stream>>>(Qb, Kb, Vt, AOb);
  pack_out_kernel<<<dim3(NOUT_), dim3(256), 0, stream>>>(wo, loA, loR, Wout);
  gemm_bt_kernel<float><<<dim3((NOUT_ + 127) / 128, S_ / 128), dim3(256), 0, stream>>>(
      AOb, Wout, C2, S_, NOUT_, D_);
  out_epilogue2_kernel<<<dim3(8, 16), dim3(256), 0, stream>>>(C2, loB, out);
}

// Round 7
// 221.308 us; speedup vs baseline: 7.3079x; 1.2397x over previous
//
#include <hip/hip_runtime.h>
#include <hip/hip_bf16.h>

static constexpr int S_    = 2048;
static constexpr int D_    = 2048;
static constexpr int NH_   = 32;
static constexpr int NKVH_ = 8;
static constexpr int HD_   = 64;
static constexpr int KVD_  = NKVH_ * HD_;   // 512
static constexpr int NQKV_ = 3288;          // 2048 q + 512 k + 512 v + 192 H + 24 logits
static constexpr int NOUT_ = 2120;          // 2048 o + 64 H + 8 logits

using bf16 = __hip_bfloat16;
typedef __attribute__((ext_vector_type(4))) float f32x4;
typedef __attribute__((ext_vector_type(8))) short s16x8;

__device__ inline unsigned short f2bf_bits(float f) {
  bf16 h = __float2bfloat16(f);
  union { bf16 b; unsigned short u; } cv; cv.b = h; return cv.u;
}
__device__ inline float bfbits2f(unsigned short u) {
  union { unsigned u32; float f; } cv; cv.u32 = (unsigned)u << 16; return cv.f;
}
__device__ inline float fexp2(float x) {
#if __has_builtin(__builtin_amdgcn_exp2f)
  return __builtin_amdgcn_exp2f(x);
#else
  return __expf(x * 0.6931471805599453f);
#endif
}

// ---------- f32 -> bf16 cast ----------
__global__ __launch_bounds__(256) void cast4_kernel(const float* __restrict__ in,
                                                    bf16* __restrict__ out, int n4) {
  int i = blockIdx.x * 256 + threadIdx.x;
  if (i >= n4) return;
  float4 v = reinterpret_cast<const float4*>(in)[i];
  ushort4 o;
  o.x = f2bf_bits(v.x); o.y = f2bf_bits(v.y); o.z = f2bf_bits(v.z); o.w = f2bf_bits(v.w);
  reinterpret_cast<ushort4*>(out)[i] = o;
}

// ---------- weight packing (concat rows, f32 -> bf16), K = 2048 ----------
__global__ __launch_bounds__(256) void pack_qkv_kernel(
    const float* __restrict__ wq, const float* __restrict__ wk, const float* __restrict__ wv,
    const float* __restrict__ lqA, const float* __restrict__ lkA, const float* __restrict__ lvA,
    const float* __restrict__ lqR, const float* __restrict__ lkR, const float* __restrict__ lvR,
    bf16* __restrict__ Wp) {
  int r = blockIdx.x;
  const float* src;
  if      (r < 2048) src = wq  + (size_t)r * 2048;
  else if (r < 2560) src = wk  + (size_t)(r - 2048) * 2048;
  else if (r < 3072) src = wv  + (size_t)(r - 2560) * 2048;
  else if (r < 3136) src = lqA + (size_t)(r - 3072) * 2048;
  else if (r < 3200) src = lkA + (size_t)(r - 3136) * 2048;
  else if (r < 3264) src = lvA + (size_t)(r - 3200) * 2048;
  else if (r < 3272) src = lqR + (size_t)(r - 3264) * 2048;
  else if (r < 3280) src = lkR + (size_t)(r - 3272) * 2048;
  else               src = lvR + (size_t)(r - 3280) * 2048;
  bf16* dst = Wp + (size_t)r * 2048;
  for (int c = threadIdx.x; c < 512; c += 256) {
    float4 v = reinterpret_cast<const float4*>(src)[c];
    ushort4 o;
    o.x = f2bf_bits(v.x); o.y = f2bf_bits(v.y); o.z = f2bf_bits(v.z); o.w = f2bf_bits(v.w);
    reinterpret_cast<ushort4*>(dst)[c] = o;
  }
}

__global__ __launch_bounds__(256) void pack_out_kernel(
    const float* __restrict__ wo, const float* __restrict__ loA,
    const float* __restrict__ loR, bf16* __restrict__ Wp) {
  int r = blockIdx.x;
  const float* src;
  if      (r < 2048) src = wo  + (size_t)r * 2048;
  else if (r < 2112) src = loA + (size_t)(r - 2048) * 2048;
  else               src = loR + (size_t)(r - 2112) * 2048;
  bf16* dst = Wp + (size_t)r * 2048;
  for (int c = threadIdx.x; c < 512; c += 256) {
    float4 v = reinterpret_cast<const float4*>(src)[c];
    ushort4 o;
    o.x = f2bf_bits(v.x); o.y = f2bf_bits(v.y); o.z = f2bf_bits(v.z); o.w = f2bf_bits(v.w);
    reinterpret_cast<ushort4*>(dst)[c] = o;
  }
}

// ---------- LoRA-B transpose-pack: Bt[col][er] bf16, cols = q|k|v|o ----------
__global__ __launch_bounds__(256) void pack_bt_kernel(
    const float* __restrict__ lqB, const float* __restrict__ lkB,
    const float* __restrict__ lvB, const float* __restrict__ loB,
    bf16* __restrict__ Bt) {
  int idx = blockIdx.x * 256 + threadIdx.x;   // 5120 cols * 8 e-chunks
  int col = idx >> 3, e = idx & 7;
  const float* src; int o, OUT;
  if (col < 2048)      { src = lqB; o = col;        OUT = 2048; }
  else if (col < 2560) { src = lkB; o = col - 2048; OUT = 512; }
  else if (col < 3072) { src = lvB; o = col - 2560; OUT = 512; }
  else                 { src = loB; o = col - 3072; OUT = 2048; }
  const float4* s4 = reinterpret_cast<const float4*>(src + ((size_t)e * OUT + o) * 8);
  float4 v0 = s4[0], v1 = s4[1];
  s16x8 p;
  p[0] = f2bf_bits(v0.x); p[1] = f2bf_bits(v0.y); p[2] = f2bf_bits(v0.z); p[3] = f2bf_bits(v0.w);
  p[4] = f2bf_bits(v1.x); p[5] = f2bf_bits(v1.y); p[6] = f2bf_bits(v1.z); p[7] = f2bf_bits(v1.w);
  *reinterpret_cast<s16x8*>(&Bt[(size_t)col * 64 + e * 8]) = p;
}

// ---------- bf16 MFMA GEMM: C[M][N] = X[M][K] @ W[N][K]^T (m97 structure) ----------
__device__ inline void gld_lds16(const void* g, void* l) {
  __builtin_amdgcn_global_load_lds((const __attribute__((address_space(1))) void*)g,
                                   (__attribute__((address_space(3))) void*)l, 16, 0, 0);
}

template <typename OT>
__global__ __launch_bounds__(256) void gemm_bt_kernel(
    const bf16* __restrict__ X, const bf16* __restrict__ W,
    OT* __restrict__ C, int M, int N, int K)
{
  __shared__ __align__(16) bf16 As[128 * 32];
  __shared__ __align__(16) bf16 Bs[128 * 32];
  const int tid = threadIdx.x;
  const int lane = tid & 63;
  const int wid = tid >> 6;
  const int m0 = blockIdx.y * 128;
  const int n0 = blockIdx.x * 128;
  const int wm = (wid >> 1) * 64;
  const int wn = (wid & 1) * 64;

  f32x4 acc[4][4] = {};
  const int kg = (lane >> 4) * 8;
  const int fr = lane & 15;

  for (int kt = 0; kt < K; kt += 32) {
    #pragma unroll
    for (int c = 0; c < 2; ++c) {
      int o  = c * 4096 + tid * 16;
      int r  = o >> 6;
      int ke = (o & 63) >> 1;
      const bf16* srcA = X + (size_t)(m0 + r) * K + kt + ke;
      gld_lds16(srcA, (char*)As + o);
      int wr = n0 + r; if (wr > N - 1) wr = N - 1;
      const bf16* srcB = W + (size_t)wr * K + kt + ke;
      gld_lds16(srcB, (char*)Bs + o);
    }
    __syncthreads();
    s16x8 af[4], bfr[4];
    #pragma unroll
    for (int i = 0; i < 4; ++i) {
      af[i]  = *reinterpret_cast<const s16x8*>(&As[(wm + i * 16 + fr) * 32 + kg]);
      bfr[i] = *reinterpret_cast<const s16x8*>(&Bs[(wn + i * 16 + fr) * 32 + kg]);
    }
    #pragma unroll
    for (int i = 0; i < 4; ++i)
      #pragma unroll
      for (int j = 0; j < 4; ++j)
        acc[i][j] = __builtin_amdgcn_mfma_f32_16x16x32_bf16(af[i], bfr[j], acc[i][j], 0, 0, 0);
    __syncthreads();
  }

  const int cr = (lane >> 4) * 4;
  const int cc = lane & 15;
  #pragma unroll
  for (int i = 0; i < 4; ++i)
    #pragma unroll
    for (int j = 0; j < 4; ++j) {
      int gn = n0 + wn + j * 16 + cc;
      if (gn >= N) continue;
      #pragma unroll
      for (int r = 0; r < 4; ++r) {
        int gm = m0 + wm + i * 16 + cr + r;
        if constexpr (__is_same(OT, bf16))
          C[(size_t)gm * N + gn] = __float2bfloat16(acc[i][j][r]);
        else
          C[(size_t)gm * N + gn] = acc[i][j][r];
      }
    }
}

// ---------- QKV epilogue v3: MFMA rank-64 apply + RoPE, tiny LDS ----------
// Block = 256 cols x 64 rows. Grid (12, 32). bx 0-7:q, 8-9:k, 10-11:v.
// out_T = mfma(a = Bt col-frag, b = Gs row-frag): lane holds row=fr,
// 4 consecutive cols per acc reg -> RoPE pairs in-lane.
__global__ __launch_bounds__(256) void qkv_epilogue3_kernel(
    const bf16* __restrict__ C1, const float* __restrict__ fc, const float* __restrict__ fs,
    const bf16* __restrict__ Bt,
    bf16* __restrict__ Qb, bf16* __restrict__ Kb, bf16* __restrict__ Vb)
{
  __shared__ __align__(16) bf16 Gs[64][72];
  const int bx = blockIdx.x;
  const int r0 = blockIdx.y * 64;
  const int t  = threadIdx.x;
  const int lane = t & 63, wid = t >> 6;
  const int fr = lane & 15, g = lane >> 4;
  int seg, opc0, pitch, btbase;
  if (bx < 8)       { seg = 0; opc0 = bx * 256;        pitch = 2048; btbase = 0; }
  else if (bx < 10) { seg = 1; opc0 = (bx - 8) * 256;  pitch = 512;  btbase = 2048; }
  else              { seg = 2; opc0 = (bx - 10) * 256; pitch = 512;  btbase = 2560; }
  const unsigned short* C1u = reinterpret_cast<const unsigned short*>(C1);

  // phase A: Gs[row][er] = bf16( 4*softmax(logits)[e] * H[row][er] )
  {
    int row = t >> 2, q4 = t & 3;
    size_t grow = (size_t)(r0 + row);
    const unsigned short* lp = C1u + grow * NQKV_ + 3264 + seg * 8;
    float l[8], mx = -1e30f;
    #pragma unroll
    for (int e = 0; e < 8; ++e) { l[e] = bfbits2f(lp[e]); mx = fmaxf(mx, l[e]); }
    float sum = 0.f;
    #pragma unroll
    for (int e = 0; e < 8; ++e) { l[e] = __expf(l[e] - mx); sum += l[e]; }
    float inv = 4.0f / sum;
    const s16x8 h0 = *reinterpret_cast<const s16x8*>(
        &C1u[grow * NQKV_ + 3072 + seg * 64 + q4 * 16]);
    const s16x8 h1 = *reinterpret_cast<const s16x8*>(
        &C1u[grow * NQKV_ + 3072 + seg * 64 + q4 * 16 + 8]);
    s16x8 g0, g1;
    #pragma unroll
    for (int j = 0; j < 8; ++j) {
      int e0 = (q4 * 16 + j) >> 3;
      int e1 = (q4 * 16 + 8 + j) >> 3;
      g0[j] = (short)f2bf_bits(l[e0] * inv * bfbits2f((unsigned short)h0[j]));
      g1[j] = (short)f2bf_bits(l[e1] * inv * bfbits2f((unsigned short)h1[j]));
    }
    *reinterpret_cast<s16x8*>(&Gs[row][q4 * 16])     = g0;
    *reinterpret_cast<s16x8*>(&Gs[row][q4 * 16 + 8]) = g1;
  }
  __syncthreads();

  // MFMA: acc[jc][i] = out_T for cols wn+jc*16+g*4+r, rows wm+i*16+fr
  const int wm = (wid >> 1) * 32;
  const int wn = (wid & 1) * 128;
  f32x4 acc[8][2] = {};
  const bf16* Btb = Bt + (size_t)btbase * 64;
  #pragma unroll
  for (int kc = 0; kc < 2; ++kc) {
    s16x8 bfrag[2];
    #pragma unroll
    for (int i = 0; i < 2; ++i)
      bfrag[i] = *reinterpret_cast<const s16x8*>(&Gs[wm + i * 16 + fr][kc * 32 + g * 8]);
    #pragma unroll
    for (int jc = 0; jc < 8; ++jc) {
      s16x8 afrag = *reinterpret_cast<const s16x8*>(
          &Btb[(size_t)(opc0 + wn + jc * 16 + fr) * 64 + kc * 32 + g * 8]);
      #pragma unroll
      for (int i = 0; i < 2; ++i)
        acc[jc][i] = __builtin_amdgcn_mfma_f32_16x16x32_bf16(afrag, bfrag[i], acc[jc][i], 0, 0, 0);
    }
  }

  // phase D: add C1 base, RoPE, store
  bf16* dst = seg == 0 ? Qb : (seg == 1 ? Kb : Vb);
  #pragma unroll
  for (int jc = 0; jc < 8; ++jc) {
    int colL = wn + jc * 16 + g * 4;
    int opc  = opc0 + colL;
    #pragma unroll
    for (int i = 0; i < 2; ++i) {
      size_t grow = (size_t)(r0 + wm + i * 16 + fr);
      uint2 bse = *reinterpret_cast<const uint2*>(&C1u[grow * NQKV_ + bx * 256 + colL]);
      float v0 = bfbits2f((unsigned short)(bse.x & 0xffff)) + acc[jc][i][0];
      float v1 = bfbits2f((unsigned short)(bse.x >> 16))    + acc[jc][i][1];
      float v2 = bfbits2f((unsigned short)(bse.y & 0xffff)) + acc[jc][i][2];
      float v3 = bfbits2f((unsigned short)(bse.y >> 16))    + acc[jc][i][3];
      uint2 o;
      if (seg < 2) {
        int hd0 = (opc >> 1) & 31;
        float c0 = fc[grow * 32 + hd0],     s0 = fs[grow * 32 + hd0];
        float c1 = fc[grow * 32 + hd0 + 1], s1 = fs[grow * 32 + hd0 + 1];
        float sc = seg == 0 ? 0.18033688f : 1.0f;   // 0.125*log2(e) for Q
        o.x = (unsigned)f2bf_bits((v0 * c0 - v1 * s0) * sc)
            | ((unsigned)f2bf_bits((v0 * s0 + v1 * c0) * sc) << 16);
        o.y = (unsigned)f2bf_bits((v2 * c1 - v3 * s1) * sc)
            | ((unsigned)f2bf_bits((v2 * s1 + v3 * c1) * sc) << 16);
      } else {
        o.x = (unsigned)f2bf_bits(v0) | ((unsigned)f2bf_bits(v1) << 16);
        o.y = (unsigned)f2bf_bits(v2) | ((unsigned)f2bf_bits(v3) << 16);
      }
      *reinterpret_cast<uint2*>(&dst[grow * pitch + opc]) = o;
    }
  }
}

// ---------- output epilogue v3: MFMA rank-64 apply, f32 out ----------
__global__ __launch_bounds__(256) void out_epilogue3_kernel(
    const float* __restrict__ C2, const bf16* __restrict__ Bt, float* __restrict__ out)
{
  __shared__ __align__(16) bf16 Gs[64][72];
  const int bx = blockIdx.x;            // 0..7
  const int r0 = blockIdx.y * 64;
  const int t  = threadIdx.x;
  const int lane = t & 63, wid = t >> 6;
  const int fr = lane & 15, g = lane >> 4;
  const int opc0 = bx * 256;

  {
    int row = t >> 2, q4 = t & 3;
    size_t grow = (size_t)(r0 + row);
    const float* lp = C2 + grow * NOUT_ + 2112;
    float l[8], mx = -1e30f;
    #pragma unroll
    for (int e = 0; e < 8; ++e) { l[e] = lp[e]; mx = fmaxf(mx, l[e]); }
    float sum = 0.f;
    #pragma unroll
    for (int e = 0; e < 8; ++e) { l[e] = __expf(l[e] - mx); sum += l[e]; }
    float inv = 4.0f / sum;
    const float* hp = C2 + grow * NOUT_ + 2048 + q4 * 16;
    s16x8 g0, g1;
    #pragma unroll
    for (int j = 0; j < 8; ++j) {
      int e0 = (q4 * 16 + j) >> 3;
      int e1 = (q4 * 16 + 8 + j) >> 3;
      g0[j] = (short)f2bf_bits(l[e0] * inv * hp[j]);
      g1[j] = (short)f2bf_bits(l[e1] * inv * hp[8 + j]);
    }
    *reinterpret_cast<s16x8*>(&Gs[row][q4 * 16])     = g0;
    *reinterpret_cast<s16x8*>(&Gs[row][q4 * 16 + 8]) = g1;
  }
  __syncthreads();

  const int wm = (wid >> 1) * 32;
  const int wn = (wid & 1) * 128;
  f32x4 acc[8][2] = {};
  const bf16* Btb = Bt + (size_t)3072 * 64;
  #pragma unroll
  for (int kc = 0; kc < 2; ++kc) {
    s16x8 bfrag[2];
    #pragma unroll
    for (int i = 0; i < 2; ++i)
      bfrag[i] = *reinterpret_cast<const s16x8*>(&Gs[wm + i * 16 + fr][kc * 32 + g * 8]);
    #pragma unroll
    for (int jc = 0; jc < 8; ++jc) {
      s16x8 afrag = *reinterpret_cast<const s16x8*>(
          &Btb[(size_t)(opc0 + wn + jc * 16 + fr) * 64 + kc * 32 + g * 8]);
      #pragma unroll
      for (int i = 0; i < 2; ++i)
        acc[jc][i] = __builtin_amdgcn_mfma_f32_16x16x32_bf16(afrag, bfrag[i], acc[jc][i], 0, 0, 0);
    }
  }

  #pragma unroll
  for (int jc = 0; jc < 8; ++jc) {
    int colL = wn + jc * 16 + g * 4;
    int opc  = opc0 + colL;
    #pragma unroll
    for (int i = 0; i < 2; ++i) {
      size_t grow = (size_t)(r0 + wm + i * 16 + fr);
      float4 base = *reinterpret_cast<const float4*>(&C2[grow * NOUT_ + opc]);
      float4 o;
      o.x = base.x + acc[jc][i][0];
      o.y = base.y + acc[jc][i][1];
      o.z = base.z + acc[jc][i][2];
      o.w = base.w + acc[jc][i][3];
      *reinterpret_cast<float4*>(&out[grow * 2048 + opc]) = o;
    }
  }
}

// ---------- V transpose (LDS-tiled): Vt[hk][d][s] = Vb[s][hk*64+d] ----------
__global__ __launch_bounds__(256) void vt2_kernel(const unsigned short* __restrict__ Vb,
                                                  unsigned short* __restrict__ Vt) {
  __shared__ unsigned short tile[64][72];
  const int hk = blockIdx.x >> 5;
  const int s0 = (blockIdx.x & 31) * 64;
  const int t  = threadIdx.x;
  #pragma unroll
  for (int r = 0; r < 2; ++r) {
    int idx = r * 256 + t;
    int row = idx >> 3, cc = idx & 7;
    *reinterpret_cast<s16x8*>(&tile[row][cc * 8]) =
        *reinterpret_cast<const s16x8*>(&Vb[(size_t)(s0 + row) * KVD_ + hk * 64 + cc * 8]);
  }
  __syncthreads();
  {
    int d = t >> 2, seg = t & 3;
    s16x8 o0;
    #pragma unroll
    for (int j = 0; j < 8; ++j) o0[j] = (short)tile[seg * 16 + j][d];
    s16x8 o1;
    #pragma unroll
    for (int j = 0; j < 8; ++j) o1[j] = (short)tile[seg * 16 + 8 + j][d];
    unsigned short* dst = Vt + ((size_t)hk * 64 + d) * S_ + s0 + seg * 16;
    *reinterpret_cast<s16x8*>(dst)     = o0;
    *reinterpret_cast<s16x8*>(dst + 8) = o1;
  }
}

// ---------- MFMA flash attention v2: 4-wave WG, LDS-staged K/V ----------
__global__ __launch_bounds__(256, 2) void attn_mfma2_kernel(
    const bf16* __restrict__ Q,   // [S][2048], pre-scaled by 0.125*log2(e)
    const bf16* __restrict__ K,   // [S][512]
    const bf16* __restrict__ Vt,  // [8][64][S]
    bf16* __restrict__ O)         // [S][2048]
{
  __shared__ __align__(16) bf16 Klds[2][2][64][32];
  __shared__ __align__(16) bf16 Vlds[2][2][64][32];
  __shared__ __align__(16) char p_all[4][32 * 144];
  const int tid  = threadIdx.x;
  const int lane = tid & 63;
  const int w    = tid >> 6;
  const int fr   = lane & 15;
  const int g    = lane >> 4;
  const int bx   = blockIdx.x;
  const int c    = 15 - (bx >> 5);            // heavy chunks first
  const int h    = bx & 31;
  const int hk   = h >> 2;
  const int q0   = c * 128 + w * 32;
  char* p_lds = p_all[w];
  const bf16* Kh  = K  + hk * 64;
  const bf16* Vth = Vt + (size_t)hk * 64 * S_;

  const int nt_wg  = 2 * c + 2;
  const int nt_me  = (q0 + 32 + 63) >> 6;
  const int nomask = (q0 + 1) >> 6;

  s16x8 qf[2][2];
  #pragma unroll
  for (int i = 0; i < 2; ++i)
    #pragma unroll
    for (int kc = 0; kc < 2; ++kc)
      qf[i][kc] = *reinterpret_cast<const s16x8*>(
          Q + (size_t)(q0 + i * 16 + fr) * 2048 + h * 64 + kc * 32 + g * 8);

  f32x4 acc[4][2] = {};
  float m[2]    = {-1e30f, -1e30f};
  float lsum[2] = {0.f, 0.f};

  #pragma unroll
  for (int r = 0; r < 2; ++r) {
    int cidx = w * 128 + r * 64 + lane;
    int kc = cidx >> 8, row = (cidx >> 2) & 63, gg = cidx & 3;
    gld_lds16(Kh  + (size_t)row * KVD_ + kc * 32 + gg * 8, (char*)Klds[0] + cidx * 16);
    gld_lds16(Vth + (size_t)row * S_   + kc * 32 + gg * 8, (char*)Vlds[0] + cidx * 16);
  }
  __syncthreads();

  int cur = 0;
  for (int t = 0; t < nt_wg; ++t) {
    const int k0 = t * 64;
    if (t + 1 < nt_wg) {
      const int k0n = k0 + 64;
      #pragma unroll
      for (int r = 0; r < 2; ++r) {
        int cidx = w * 128 + r * 64 + lane;
        int kc = cidx >> 8, row = (cidx >> 2) & 63, gg = cidx & 3;
        gld_lds16(Kh  + (size_t)(k0n + row) * KVD_ + kc * 32 + gg * 8,
                  (char*)Klds[cur ^ 1] + cidx * 16);
        gld_lds16(Vth + (size_t)row * S_ + k0n + kc * 32 + gg * 8,
                  (char*)Vlds[cur ^ 1] + cidx * 16);
      }
    }
    if (t < nt_me) {
      f32x4 st[4][2] = {};
      __builtin_amdgcn_s_setprio(1);
      #pragma unroll
      for (int kc = 0; kc < 2; ++kc)
        #pragma unroll
        for (int kt = 0; kt < 4; ++kt) {
          s16x8 kf = *reinterpret_cast<const s16x8*>(&Klds[cur][kc][kt * 16 + fr][g * 8]);
          #pragma unroll
          for (int i = 0; i < 2; ++i)
            st[kt][i] = __builtin_amdgcn_mfma_f32_16x16x32_bf16(kf, qf[i][kc], st[kt][i], 0, 0, 0);
        }
      __builtin_amdgcn_s_setprio(0);

      if (t >= nomask) {
        #pragma unroll
        for (int kt = 0; kt < 4; ++kt)
          #pragma unroll
          for (int i = 0; i < 2; ++i)
            #pragma unroll
            for (int r = 0; r < 4; ++r) {
              int key = k0 + kt * 16 + g * 4 + r;
              int q   = q0 + i * 16 + fr;
              if (key > q) st[kt][i][r] = -1e30f;
            }
      }

      #pragma unroll
      for (int i = 0; i < 2; ++i) {
        float tm = -1e30f;
        #pragma unroll
        for (int kt = 0; kt < 4; ++kt)
          #pragma unroll
          for (int r = 0; r < 4; ++r)
            tm = fmaxf(tm, st[kt][i][r]);
        tm = fmaxf(tm, __shfl_xor(tm, 16));
        tm = fmaxf(tm, __shfl_xor(tm, 32));
        float newm = m[i];
        if (!__all(tm <= m[i] + 8.f)) {
          newm = fmaxf(m[i], tm);
          float rs = fexp2(m[i] - newm);
          lsum[i] *= rs;
          #pragma unroll
          for (int dt = 0; dt < 4; ++dt)
            #pragma unroll
            for (int r = 0; r < 4; ++r)
              acc[dt][i][r] *= rs;
          m[i] = newm;
        }
        #pragma unroll
        for (int kt = 0; kt < 4; ++kt) {
          float p0 = fexp2(st[kt][i][0] - newm);
          float p1 = fexp2(st[kt][i][1] - newm);
          float p2 = fexp2(st[kt][i][2] - newm);
          float p3 = fexp2(st[kt][i][3] - newm);
          lsum[i] += (p0 + p1) + (p2 + p3);
          uint2 pw;
          pw.x = (unsigned)f2bf_bits(p0) | ((unsigned)f2bf_bits(p1) << 16);
          pw.y = (unsigned)f2bf_bits(p2) | ((unsigned)f2bf_bits(p3) << 16);
          *reinterpret_cast<uint2*>(p_lds + (i * 16 + fr) * 144 + (kt * 16 + g * 4) * 2) = pw;
        }
      }

      __builtin_amdgcn_s_setprio(1);
      #pragma unroll
      for (int kc = 0; kc < 2; ++kc) {
        s16x8 pf[2];
        #pragma unroll
        for (int i = 0; i < 2; ++i)
          pf[i] = *reinterpret_cast<const s16x8*>(
              p_lds + (i * 16 + fr) * 144 + (kc * 32 + g * 8) * 2);
        #pragma unroll
        for (int dt = 0; dt < 4; ++dt) {
          s16x8 vf = *reinterpret_cast<const s16x8*>(&Vlds[cur][kc][dt * 16 + fr][g * 8]);
          #pragma unroll
          for (int i = 0; i < 2; ++i)
            acc[dt][i] = __builtin_amdgcn_mfma_f32_16x16x32_bf16(vf, pf[i], acc[dt][i], 0, 0, 0);
        }
      }
      __builtin_amdgcn_s_setprio(0);
    }
    __syncthreads();
    cur ^= 1;
  }

  #pragma unroll
  for (int i = 0; i < 2; ++i) {
    lsum[i] += __shfl_xor(lsum[i], 16);
    lsum[i] += __shfl_xor(lsum[i], 32);
  }
  float inv0 = 1.f / lsum[0], inv1 = 1.f / lsum[1];
  #pragma unroll
  for (int i = 0; i < 2; ++i) {
    float inv = i ? inv1 : inv0;
    #pragma unroll
    for (int dt = 0; dt < 4; ++dt)
      #pragma unroll
      for (int r2 = 0; r2 < 2; ++r2) {
        unsigned o = (unsigned)f2bf_bits(acc[dt][i][2 * r2] * inv)
                   | ((unsigned)f2bf_bits(acc[dt][i][2 * r2 + 1] * inv) << 16);
        size_t off = (size_t)(q0 + i * 16 + fr) * 2048 + h * 64 + dt * 16 + g * 4 + 2 * r2;
        *reinterpret_cast<unsigned*>(O + off) = o;
      }
  }
}

extern "C" void kernel_launch(void* const* d_in, const int* in_sizes, int n_in,
                              void* d_out, int out_size, void* d_ws, size_t ws_size,
                              hipStream_t stream) {
  const float* x   = (const float*)d_in[0];
  const float* fc  = (const float*)d_in[3];
  const float* fs  = (const float*)d_in[4];
  const float* wq  = (const float*)d_in[5];
  const float* wk  = (const float*)d_in[6];
  const float* wv  = (const float*)d_in[7];
  const float* wo  = (const float*)d_in[8];
  const float* lqR = (const float*)d_in[9];
  const float* lqA = (const float*)d_in[10];
  const float* lqB = (const float*)d_in[11];
  const float* lkR = (const float*)d_in[12];
  const float* lkA = (const float*)d_in[13];
  const float* lkB = (const float*)d_in[14];
  const float* lvR = (const float*)d_in[15];
  const float* lvA = (const float*)d_in[16];
  const float* lvB = (const float*)d_in[17];
  const float* loR = (const float*)d_in[18];
  const float* loA = (const float*)d_in[19];
  const float* loB = (const float*)d_in[20];
  float* out = (float*)d_out;
  char* ws = (char*)d_ws;

  if (ws_size < 58000000u) return;

  bf16* xb   = (bf16*)(ws + 0);            // 8 MB; aliased as AOb after gemm1
  bf16* Wqkv = (bf16*)(ws + 8388608);      // 13.47 MB; aliased as Wout after gemm1
  bf16* Qb   = (bf16*)(ws + 21856256);     // 8 MB
  bf16* Kb   = (bf16*)(ws + 30244864);     // 2 MB
  bf16* Vb   = (bf16*)(ws + 32342016);     // 2 MB
  bf16* Vt   = (bf16*)(ws + 34439168);     // 2 MB
  bf16* C1   = (bf16*)(ws + 36536320);     // 13.47 MB (dead after qkv epilogue)
  bf16* Bt   = (bf16*)(ws + 50003968);     // 640 KB packed LoRA-B (q|k|v|o)
  float* C2  = (float*)(ws + 21856256);    // 17.37 MB, overlays Qb..C1-head (all dead)
  bf16* AOb  = xb;
  bf16* Wout = Wqkv;

  cast4_kernel<<<dim3(S_ * D_ / 4 / 256), dim3(256), 0, stream>>>(x, xb, S_ * D_ / 4);
  pack_qkv_kernel<<<dim3(NQKV_), dim3(256), 0, stream>>>(wq, wk, wv, lqA, lkA, lvA,
                                                         lqR, lkR, lvR, Wqkv);
  pack_bt_kernel<<<dim3(160), dim3(256), 0, stream>>>(lqB, lkB, lvB, loB, Bt);
  gemm_bt_kernel<bf16><<<dim3((NQKV_ + 127) / 128, S_ / 128), dim3(256), 0, stream>>>(
      xb, Wqkv, C1, S_, NQKV_, D_);
  qkv_epilogue3_kernel<<<dim3(12, 32), dim3(256), 0, stream>>>(C1, fc, fs, Bt, Qb, Kb, Vb);
  vt2_kernel<<<dim3(256), dim3(256), 0, stream>>>((const unsigned short*)Vb,
                                                  (unsigned short*)Vt);
  attn_mfma2_kernel<<<dim3(512), dim3(256), 0, stream>>>(Qb, Kb, Vt, AOb);
  pack_out_kernel<<<dim3(NOUT_), dim3(256), 0, stream>>>(wo, loA, loR, Wout);
  gemm_bt_kernel<float><<<dim3((NOUT_ + 127) / 128, S_ / 128), dim3(256), 0, stream>>>(
      AOb, Wout, C2, S_, NOUT_, D_);
  out_epilogue3_kernel<<<dim3(8, 32), dim3(256), 0, stream>>>(C2, Bt, out);
}

// Round 8
// 209.098 us; speedup vs baseline: 7.7346x; 1.0584x over previous
//
#include <hip/hip_runtime.h>
#include <hip/hip_bf16.h>

static constexpr int S_    = 2048;
static constexpr int D_    = 2048;
static constexpr int NH_   = 32;
static constexpr int NKVH_ = 8;
static constexpr int HD_   = 64;
static constexpr int KVD_  = NKVH_ * HD_;   // 512
static constexpr int NQKV_ = 3288;          // 2048 q + 512 k + 512 v + 192 H + 24 logits
static constexpr int NOUT_ = 2120;          // 2048 o + 64 H + 8 logits

using bf16 = __hip_bfloat16;
typedef __attribute__((ext_vector_type(4))) float f32x4;
typedef __attribute__((ext_vector_type(8))) short s16x8;

__device__ inline unsigned short f2bf_bits(float f) {
  bf16 h = __float2bfloat16(f);
  union { bf16 b; unsigned short u; } cv; cv.b = h; return cv.u;
}
__device__ inline float bfbits2f(unsigned short u) {
  union { unsigned u32; float f; } cv; cv.u32 = (unsigned)u << 16; return cv.f;
}
__device__ inline float fexp2(float x) {
#if __has_builtin(__builtin_amdgcn_exp2f)
  return __builtin_amdgcn_exp2f(x);
#else
  return __expf(x * 0.6931471805599453f);
#endif
}

// ---------- f32 -> bf16 cast ----------
__global__ __launch_bounds__(256) void cast4_kernel(const float* __restrict__ in,
                                                    bf16* __restrict__ out, int n4) {
  int i = blockIdx.x * 256 + threadIdx.x;
  if (i >= n4) return;
  float4 v = reinterpret_cast<const float4*>(in)[i];
  ushort4 o;
  o.x = f2bf_bits(v.x); o.y = f2bf_bits(v.y); o.z = f2bf_bits(v.z); o.w = f2bf_bits(v.w);
  reinterpret_cast<ushort4*>(out)[i] = o;
}

// ---------- weight packing (concat rows, f32 -> bf16), K = 2048 ----------
__global__ __launch_bounds__(256) void pack_qkv_kernel(
    const float* __restrict__ wq, const float* __restrict__ wk, const float* __restrict__ wv,
    const float* __restrict__ lqA, const float* __restrict__ lkA, const float* __restrict__ lvA,
    const float* __restrict__ lqR, const float* __restrict__ lkR, const float* __restrict__ lvR,
    bf16* __restrict__ Wp) {
  int r = blockIdx.x;
  const float* src;
  if      (r < 2048) src = wq  + (size_t)r * 2048;
  else if (r < 2560) src = wk  + (size_t)(r - 2048) * 2048;
  else if (r < 3072) src = wv  + (size_t)(r - 2560) * 2048;
  else if (r < 3136) src = lqA + (size_t)(r - 3072) * 2048;
  else if (r < 3200) src = lkA + (size_t)(r - 3136) * 2048;
  else if (r < 3264) src = lvA + (size_t)(r - 3200) * 2048;
  else if (r < 3272) src = lqR + (size_t)(r - 3264) * 2048;
  else if (r < 3280) src = lkR + (size_t)(r - 3272) * 2048;
  else               src = lvR + (size_t)(r - 3280) * 2048;
  bf16* dst = Wp + (size_t)r * 2048;
  for (int c = threadIdx.x; c < 512; c += 256) {
    float4 v = reinterpret_cast<const float4*>(src)[c];
    ushort4 o;
    o.x = f2bf_bits(v.x); o.y = f2bf_bits(v.y); o.z = f2bf_bits(v.z); o.w = f2bf_bits(v.w);
    reinterpret_cast<ushort4*>(dst)[c] = o;
  }
}

__global__ __launch_bounds__(256) void pack_out_kernel(
    const float* __restrict__ wo, const float* __restrict__ loA,
    const float* __restrict__ loR, bf16* __restrict__ Wp) {
  int r = blockIdx.x;
  const float* src;
  if      (r < 2048) src = wo  + (size_t)r * 2048;
  else if (r < 2112) src = loA + (size_t)(r - 2048) * 2048;
  else               src = loR + (size_t)(r - 2112) * 2048;
  bf16* dst = Wp + (size_t)r * 2048;
  for (int c = threadIdx.x; c < 512; c += 256) {
    float4 v = reinterpret_cast<const float4*>(src)[c];
    ushort4 o;
    o.x = f2bf_bits(v.x); o.y = f2bf_bits(v.y); o.z = f2bf_bits(v.z); o.w = f2bf_bits(v.w);
    reinterpret_cast<ushort4*>(dst)[c] = o;
  }
}

// ---------- LoRA-B transpose-pack: Bt[col][er] bf16, cols = q|k|v|o ----------
__global__ __launch_bounds__(256) void pack_bt_kernel(
    const float* __restrict__ lqB, const float* __restrict__ lkB,
    const float* __restrict__ lvB, const float* __restrict__ loB,
    bf16* __restrict__ Bt) {
  int idx = blockIdx.x * 256 + threadIdx.x;   // 5120 cols * 8 e-chunks
  int col = idx >> 3, e = idx & 7;
  const float* src; int o, OUT;
  if (col < 2048)      { src = lqB; o = col;        OUT = 2048; }
  else if (col < 2560) { src = lkB; o = col - 2048; OUT = 512; }
  else if (col < 3072) { src = lvB; o = col - 2560; OUT = 512; }
  else                 { src = loB; o = col - 3072; OUT = 2048; }
  const float4* s4 = reinterpret_cast<const float4*>(src + ((size_t)e * OUT + o) * 8);
  float4 v0 = s4[0], v1 = s4[1];
  s16x8 p;
  p[0] = f2bf_bits(v0.x); p[1] = f2bf_bits(v0.y); p[2] = f2bf_bits(v0.z); p[3] = f2bf_bits(v0.w);
  p[4] = f2bf_bits(v1.x); p[5] = f2bf_bits(v1.y); p[6] = f2bf_bits(v1.z); p[7] = f2bf_bits(v1.w);
  *reinterpret_cast<s16x8*>(&Bt[(size_t)col * 64 + e * 8]) = p;
}

// ---------- bf16 MFMA GEMM v2: double-buffered LDS, 1 barrier / K-step ----------
__device__ inline void gld_lds16(const void* g, void* l) {
  __builtin_amdgcn_global_load_lds((const __attribute__((address_space(1))) void*)g,
                                   (__attribute__((address_space(3))) void*)l, 16, 0, 0);
}

template <typename OT>
__global__ __launch_bounds__(256) void gemm_bt_kernel(
    const bf16* __restrict__ X, const bf16* __restrict__ W,
    OT* __restrict__ C, int M, int N, int K)
{
  __shared__ __align__(16) bf16 As[2][128 * 32];
  __shared__ __align__(16) bf16 Bs[2][128 * 32];
  const int tid = threadIdx.x;
  const int lane = tid & 63;
  const int wid = tid >> 6;
  const int m0 = blockIdx.y * 128;
  const int n0 = blockIdx.x * 128;
  const int wm = (wid >> 1) * 64;
  const int wn = (wid & 1) * 64;

  f32x4 acc[4][4] = {};
  const int kg = (lane >> 4) * 8;
  const int fr = lane & 15;

  // staging coords: chunk c -> byte o = c*4096 + tid*16; row = o>>6; kelem = (o&63)>>1
  const int o0 = tid * 16;
  const int r0 = o0 >> 6;
  const int ke0 = (o0 & 63) >> 1;
  const int o1 = 4096 + tid * 16;
  const int r1 = o1 >> 6;
  const int ke1 = (o1 & 63) >> 1;
  int wr0 = n0 + r0; if (wr0 > N - 1) wr0 = N - 1;
  int wr1 = n0 + r1; if (wr1 > N - 1) wr1 = N - 1;
  const bf16* xa0 = X + (size_t)(m0 + r0) * K + ke0;
  const bf16* xa1 = X + (size_t)(m0 + r1) * K + ke1;
  const bf16* wa0 = W + (size_t)wr0 * K + ke0;
  const bf16* wa1 = W + (size_t)wr1 * K + ke1;

  // prologue: stage tile 0 into buf 0
  gld_lds16(xa0, (char*)As[0] + o0);
  gld_lds16(wa0, (char*)Bs[0] + o0);
  gld_lds16(xa1, (char*)As[0] + o1);
  gld_lds16(wa1, (char*)Bs[0] + o1);
  __syncthreads();

  int cur = 0;
  for (int kt = 0; kt < K; kt += 32) {
    if (kt + 32 < K) {
      // issue next-tile staging BEFORE compute; barrier at end drains it
      gld_lds16(xa0 + kt + 32, (char*)As[cur ^ 1] + o0);
      gld_lds16(wa0 + kt + 32, (char*)Bs[cur ^ 1] + o0);
      gld_lds16(xa1 + kt + 32, (char*)As[cur ^ 1] + o1);
      gld_lds16(wa1 + kt + 32, (char*)Bs[cur ^ 1] + o1);
    }
    s16x8 af[4], bfr[4];
    #pragma unroll
    for (int i = 0; i < 4; ++i) {
      af[i]  = *reinterpret_cast<const s16x8*>(&As[cur][(wm + i * 16 + fr) * 32 + kg]);
      bfr[i] = *reinterpret_cast<const s16x8*>(&Bs[cur][(wn + i * 16 + fr) * 32 + kg]);
    }
    #pragma unroll
    for (int i = 0; i < 4; ++i)
      #pragma unroll
      for (int j = 0; j < 4; ++j)
        acc[i][j] = __builtin_amdgcn_mfma_f32_16x16x32_bf16(af[i], bfr[j], acc[i][j], 0, 0, 0);
    __syncthreads();
    cur ^= 1;
  }

  const int cr = (lane >> 4) * 4;
  const int cc = lane & 15;
  #pragma unroll
  for (int i = 0; i < 4; ++i)
    #pragma unroll
    for (int j = 0; j < 4; ++j) {
      int gn = n0 + wn + j * 16 + cc;
      if (gn >= N) continue;
      #pragma unroll
      for (int r = 0; r < 4; ++r) {
        int gm = m0 + wm + i * 16 + cr + r;
        if constexpr (__is_same(OT, bf16))
          C[(size_t)gm * N + gn] = __float2bfloat16(acc[i][j][r]);
        else
          C[(size_t)gm * N + gn] = acc[i][j][r];
      }
    }
}

// ---------- QKV epilogue v3: MFMA rank-64 apply + RoPE, tiny LDS ----------
__global__ __launch_bounds__(256) void qkv_epilogue3_kernel(
    const bf16* __restrict__ C1, const float* __restrict__ fc, const float* __restrict__ fs,
    const bf16* __restrict__ Bt,
    bf16* __restrict__ Qb, bf16* __restrict__ Kb, bf16* __restrict__ Vb)
{
  __shared__ __align__(16) bf16 Gs[64][72];
  const int bx = blockIdx.x;
  const int r0 = blockIdx.y * 64;
  const int t  = threadIdx.x;
  const int lane = t & 63, wid = t >> 6;
  const int fr = lane & 15, g = lane >> 4;
  int seg, opc0, pitch, btbase;
  if (bx < 8)       { seg = 0; opc0 = bx * 256;        pitch = 2048; btbase = 0; }
  else if (bx < 10) { seg = 1; opc0 = (bx - 8) * 256;  pitch = 512;  btbase = 2048; }
  else              { seg = 2; opc0 = (bx - 10) * 256; pitch = 512;  btbase = 2560; }
  const unsigned short* C1u = reinterpret_cast<const unsigned short*>(C1);

  {
    int row = t >> 2, q4 = t & 3;
    size_t grow = (size_t)(r0 + row);
    const unsigned short* lp = C1u + grow * NQKV_ + 3264 + seg * 8;
    float l[8], mx = -1e30f;
    #pragma unroll
    for (int e = 0; e < 8; ++e) { l[e] = bfbits2f(lp[e]); mx = fmaxf(mx, l[e]); }
    float sum = 0.f;
    #pragma unroll
    for (int e = 0; e < 8; ++e) { l[e] = __expf(l[e] - mx); sum += l[e]; }
    float inv = 4.0f / sum;
    const s16x8 h0 = *reinterpret_cast<const s16x8*>(
        &C1u[grow * NQKV_ + 3072 + seg * 64 + q4 * 16]);
    const s16x8 h1 = *reinterpret_cast<const s16x8*>(
        &C1u[grow * NQKV_ + 3072 + seg * 64 + q4 * 16 + 8]);
    s16x8 g0, g1;
    #pragma unroll
    for (int j = 0; j < 8; ++j) {
      int e0 = (q4 * 16 + j) >> 3;
      int e1 = (q4 * 16 + 8 + j) >> 3;
      g0[j] = (short)f2bf_bits(l[e0] * inv * bfbits2f((unsigned short)h0[j]));
      g1[j] = (short)f2bf_bits(l[e1] * inv * bfbits2f((unsigned short)h1[j]));
    }
    *reinterpret_cast<s16x8*>(&Gs[row][q4 * 16])     = g0;
    *reinterpret_cast<s16x8*>(&Gs[row][q4 * 16 + 8]) = g1;
  }
  __syncthreads();

  const int wm = (wid >> 1) * 32;
  const int wn = (wid & 1) * 128;
  f32x4 acc[8][2] = {};
  const bf16* Btb = Bt + (size_t)btbase * 64;
  #pragma unroll
  for (int kc = 0; kc < 2; ++kc) {
    s16x8 bfrag[2];
    #pragma unroll
    for (int i = 0; i < 2; ++i)
      bfrag[i] = *reinterpret_cast<const s16x8*>(&Gs[wm + i * 16 + fr][kc * 32 + g * 8]);
    #pragma unroll
    for (int jc = 0; jc < 8; ++jc) {
      s16x8 afrag = *reinterpret_cast<const s16x8*>(
          &Btb[(size_t)(opc0 + wn + jc * 16 + fr) * 64 + kc * 32 + g * 8]);
      #pragma unroll
      for (int i = 0; i < 2; ++i)
        acc[jc][i] = __builtin_amdgcn_mfma_f32_16x16x32_bf16(afrag, bfrag[i], acc[jc][i], 0, 0, 0);
    }
  }

  bf16* dst = seg == 0 ? Qb : (seg == 1 ? Kb : Vb);
  #pragma unroll
  for (int jc = 0; jc < 8; ++jc) {
    int colL = wn + jc * 16 + g * 4;
    int opc  = opc0 + colL;
    #pragma unroll
    for (int i = 0; i < 2; ++i) {
      size_t grow = (size_t)(r0 + wm + i * 16 + fr);
      uint2 bse = *reinterpret_cast<const uint2*>(&C1u[grow * NQKV_ + bx * 256 + colL]);
      float v0 = bfbits2f((unsigned short)(bse.x & 0xffff)) + acc[jc][i][0];
      float v1 = bfbits2f((unsigned short)(bse.x >> 16))    + acc[jc][i][1];
      float v2 = bfbits2f((unsigned short)(bse.y & 0xffff)) + acc[jc][i][2];
      float v3 = bfbits2f((unsigned short)(bse.y >> 16))    + acc[jc][i][3];
      uint2 o;
      if (seg < 2) {
        int hd0 = (opc >> 1) & 31;
        float c0 = fc[grow * 32 + hd0],     s0 = fs[grow * 32 + hd0];
        float c1 = fc[grow * 32 + hd0 + 1], s1 = fs[grow * 32 + hd0 + 1];
        float sc = seg == 0 ? 0.18033688f : 1.0f;   // 0.125*log2(e) for Q
        o.x = (unsigned)f2bf_bits((v0 * c0 - v1 * s0) * sc)
            | ((unsigned)f2bf_bits((v0 * s0 + v1 * c0) * sc) << 16);
        o.y = (unsigned)f2bf_bits((v2 * c1 - v3 * s1) * sc)
            | ((unsigned)f2bf_bits((v2 * s1 + v3 * c1) * sc) << 16);
      } else {
        o.x = (unsigned)f2bf_bits(v0) | ((unsigned)f2bf_bits(v1) << 16);
        o.y = (unsigned)f2bf_bits(v2) | ((unsigned)f2bf_bits(v3) << 16);
      }
      *reinterpret_cast<uint2*>(&dst[grow * pitch + opc]) = o;
    }
  }
}

// ---------- output epilogue v3: MFMA rank-64 apply, f32 out ----------
__global__ __launch_bounds__(256) void out_epilogue3_kernel(
    const float* __restrict__ C2, const bf16* __restrict__ Bt, float* __restrict__ out)
{
  __shared__ __align__(16) bf16 Gs[64][72];
  const int bx = blockIdx.x;            // 0..7
  const int r0 = blockIdx.y * 64;
  const int t  = threadIdx.x;
  const int lane = t & 63, wid = t >> 6;
  const int fr = lane & 15, g = lane >> 4;
  const int opc0 = bx * 256;

  {
    int row = t >> 2, q4 = t & 3;
    size_t grow = (size_t)(r0 + row);
    const float* lp = C2 + grow * NOUT_ + 2112;
    float l[8], mx = -1e30f;
    #pragma unroll
    for (int e = 0; e < 8; ++e) { l[e] = lp[e]; mx = fmaxf(mx, l[e]); }
    float sum = 0.f;
    #pragma unroll
    for (int e = 0; e < 8; ++e) { l[e] = __expf(l[e] - mx); sum += l[e]; }
    float inv = 4.0f / sum;
    const float* hp = C2 + grow * NOUT_ + 2048 + q4 * 16;
    s16x8 g0, g1;
    #pragma unroll
    for (int j = 0; j < 8; ++j) {
      int e0 = (q4 * 16 + j) >> 3;
      int e1 = (q4 * 16 + 8 + j) >> 3;
      g0[j] = (short)f2bf_bits(l[e0] * inv * hp[j]);
      g1[j] = (short)f2bf_bits(l[e1] * inv * hp[8 + j]);
    }
    *reinterpret_cast<s16x8*>(&Gs[row][q4 * 16])     = g0;
    *reinterpret_cast<s16x8*>(&Gs[row][q4 * 16 + 8]) = g1;
  }
  __syncthreads();

  const int wm = (wid >> 1) * 32;
  const int wn = (wid & 1) * 128;
  f32x4 acc[8][2] = {};
  const bf16* Btb = Bt + (size_t)3072 * 64;
  #pragma unroll
  for (int kc = 0; kc < 2; ++kc) {
    s16x8 bfrag[2];
    #pragma unroll
    for (int i = 0; i < 2; ++i)
      bfrag[i] = *reinterpret_cast<const s16x8*>(&Gs[wm + i * 16 + fr][kc * 32 + g * 8]);
    #pragma unroll
    for (int jc = 0; jc < 8; ++jc) {
      s16x8 afrag = *reinterpret_cast<const s16x8*>(
          &Btb[(size_t)(opc0 + wn + jc * 16 + fr) * 64 + kc * 32 + g * 8]);
      #pragma unroll
      for (int i = 0; i < 2; ++i)
        acc[jc][i] = __builtin_amdgcn_mfma_f32_16x16x32_bf16(afrag, bfrag[i], acc[jc][i], 0, 0, 0);
    }
  }

  #pragma unroll
  for (int jc = 0; jc < 8; ++jc) {
    int colL = wn + jc * 16 + g * 4;
    int opc  = opc0 + colL;
    #pragma unroll
    for (int i = 0; i < 2; ++i) {
      size_t grow = (size_t)(r0 + wm + i * 16 + fr);
      float4 base = *reinterpret_cast<const float4*>(&C2[grow * NOUT_ + opc]);
      float4 o;
      o.x = base.x + acc[jc][i][0];
      o.y = base.y + acc[jc][i][1];
      o.z = base.z + acc[jc][i][2];
      o.w = base.w + acc[jc][i][3];
      *reinterpret_cast<float4*>(&out[grow * 2048 + opc]) = o;
    }
  }
}

// ---------- V transpose (LDS-tiled): Vt[hk][d][s] = Vb[s][hk*64+d] ----------
__global__ __launch_bounds__(256) void vt2_kernel(const unsigned short* __restrict__ Vb,
                                                  unsigned short* __restrict__ Vt) {
  __shared__ unsigned short tile[64][72];
  const int hk = blockIdx.x >> 5;
  const int s0 = (blockIdx.x & 31) * 64;
  const int t  = threadIdx.x;
  #pragma unroll
  for (int r = 0; r < 2; ++r) {
    int idx = r * 256 + t;
    int row = idx >> 3, cc = idx & 7;
    *reinterpret_cast<s16x8*>(&tile[row][cc * 8]) =
        *reinterpret_cast<const s16x8*>(&Vb[(size_t)(s0 + row) * KVD_ + hk * 64 + cc * 8]);
  }
  __syncthreads();
  {
    int d = t >> 2, seg = t & 3;
    s16x8 o0;
    #pragma unroll
    for (int j = 0; j < 8; ++j) o0[j] = (short)tile[seg * 16 + j][d];
    s16x8 o1;
    #pragma unroll
    for (int j = 0; j < 8; ++j) o1[j] = (short)tile[seg * 16 + 8 + j][d];
    unsigned short* dst = Vt + ((size_t)hk * 64 + d) * S_ + s0 + seg * 16;
    *reinterpret_cast<s16x8*>(dst)     = o0;
    *reinterpret_cast<s16x8*>(dst + 8) = o1;
  }
}

// ---------- MFMA flash attention v2: 4-wave WG, LDS-staged K/V ----------
__global__ __launch_bounds__(256, 2) void attn_mfma2_kernel(
    const bf16* __restrict__ Q,   // [S][2048], pre-scaled by 0.125*log2(e)
    const bf16* __restrict__ K,   // [S][512]
    const bf16* __restrict__ Vt,  // [8][64][S]
    bf16* __restrict__ O)         // [S][2048]
{
  __shared__ __align__(16) bf16 Klds[2][2][64][32];
  __shared__ __align__(16) bf16 Vlds[2][2][64][32];
  __shared__ __align__(16) char p_all[4][32 * 144];
  const int tid  = threadIdx.x;
  const int lane = tid & 63;
  const int w    = tid >> 6;
  const int fr   = lane & 15;
  const int g    = lane >> 4;
  const int bx   = blockIdx.x;
  const int c    = 15 - (bx >> 5);            // heavy chunks first
  const int h    = bx & 31;
  const int hk   = h >> 2;
  const int q0   = c * 128 + w * 32;
  char* p_lds = p_all[w];
  const bf16* Kh  = K  + hk * 64;
  const bf16* Vth = Vt + (size_t)hk * 64 * S_;

  const int nt_wg  = 2 * c + 2;
  const int nt_me  = (q0 + 32 + 63) >> 6;
  const int nomask = (q0 + 1) >> 6;

  s16x8 qf[2][2];
  #pragma unroll
  for (int i = 0; i < 2; ++i)
    #pragma unroll
    for (int kc = 0; kc < 2; ++kc)
      qf[i][kc] = *reinterpret_cast<const s16x8*>(
          Q + (size_t)(q0 + i * 16 + fr) * 2048 + h * 64 + kc * 32 + g * 8);

  f32x4 acc[4][2] = {};
  float m[2]    = {-1e30f, -1e30f};
  float lsum[2] = {0.f, 0.f};

  #pragma unroll
  for (int r = 0; r < 2; ++r) {
    int cidx = w * 128 + r * 64 + lane;
    int kc = cidx >> 8, row = (cidx >> 2) & 63, gg = cidx & 3;
    gld_lds16(Kh  + (size_t)row * KVD_ + kc * 32 + gg * 8, (char*)Klds[0] + cidx * 16);
    gld_lds16(Vth + (size_t)row * S_   + kc * 32 + gg * 8, (char*)Vlds[0] + cidx * 16);
  }
  __syncthreads();

  int cur = 0;
  for (int t = 0; t < nt_wg; ++t) {
    const int k0 = t * 64;
    if (t + 1 < nt_wg) {
      const int k0n = k0 + 64;
      #pragma unroll
      for (int r = 0; r < 2; ++r) {
        int cidx = w * 128 + r * 64 + lane;
        int kc = cidx >> 8, row = (cidx >> 2) & 63, gg = cidx & 3;
        gld_lds16(Kh  + (size_t)(k0n + row) * KVD_ + kc * 32 + gg * 8,
                  (char*)Klds[cur ^ 1] + cidx * 16);
        gld_lds16(Vth + (size_t)row * S_ + k0n + kc * 32 + gg * 8,
                  (char*)Vlds[cur ^ 1] + cidx * 16);
      }
    }
    if (t < nt_me) {
      f32x4 st[4][2] = {};
      __builtin_amdgcn_s_setprio(1);
      #pragma unroll
      for (int kc = 0; kc < 2; ++kc)
        #pragma unroll
        for (int kt = 0; kt < 4; ++kt) {
          s16x8 kf = *reinterpret_cast<const s16x8*>(&Klds[cur][kc][kt * 16 + fr][g * 8]);
          #pragma unroll
          for (int i = 0; i < 2; ++i)
            st[kt][i] = __builtin_amdgcn_mfma_f32_16x16x32_bf16(kf, qf[i][kc], st[kt][i], 0, 0, 0);
        }
      __builtin_amdgcn_s_setprio(0);

      if (t >= nomask) {
        #pragma unroll
        for (int kt = 0; kt < 4; ++kt)
          #pragma unroll
          for (int i = 0; i < 2; ++i)
            #pragma unroll
            for (int r = 0; r < 4; ++r) {
              int key = k0 + kt * 16 + g * 4 + r;
              int q   = q0 + i * 16 + fr;
              if (key > q) st[kt][i][r] = -1e30f;
            }
      }

      #pragma unroll
      for (int i = 0; i < 2; ++i) {
        float tm = -1e30f;
        #pragma unroll
        for (int kt = 0; kt < 4; ++kt)
          #pragma unroll
          for (int r = 0; r < 4; ++r)
            tm = fmaxf(tm, st[kt][i][r]);
        tm = fmaxf(tm, __shfl_xor(tm, 16));
        tm = fmaxf(tm, __shfl_xor(tm, 32));
        float newm = m[i];
        if (!__all(tm <= m[i] + 8.f)) {
          newm = fmaxf(m[i], tm);
          float rs = fexp2(m[i] - newm);
          lsum[i] *= rs;
          #pragma unroll
          for (int dt = 0; dt < 4; ++dt)
            #pragma unroll
            for (int r = 0; r < 4; ++r)
              acc[dt][i][r] *= rs;
          m[i] = newm;
        }
        #pragma unroll
        for (int kt = 0; kt < 4; ++kt) {
          float p0 = fexp2(st[kt][i][0] - newm);
          float p1 = fexp2(st[kt][i][1] - newm);
          float p2 = fexp2(st[kt][i][2] - newm);
          float p3 = fexp2(st[kt][i][3] - newm);
          lsum[i] += (p0 + p1) + (p2 + p3);
          uint2 pw;
          pw.x = (unsigned)f2bf_bits(p0) | ((unsigned)f2bf_bits(p1) << 16);
          pw.y = (unsigned)f2bf_bits(p2) | ((unsigned)f2bf_bits(p3) << 16);
          *reinterpret_cast<uint2*>(p_lds + (i * 16 + fr) * 144 + (kt * 16 + g * 4) * 2) = pw;
        }
      }

      __builtin_amdgcn_s_setprio(1);
      #pragma unroll
      for (int kc = 0; kc < 2; ++kc) {
        s16x8 pf[2];
        #pragma unroll
        for (int i = 0; i < 2; ++i)
          pf[i] = *reinterpret_cast<const s16x8*>(
              p_lds + (i * 16 + fr) * 144 + (kc * 32 + g * 8) * 2);
        #pragma unroll
        for (int dt = 0; dt < 4; ++dt) {
          s16x8 vf = *reinterpret_cast<const s16x8*>(&Vlds[cur][kc][dt * 16 + fr][g * 8]);
          #pragma unroll
          for (int i = 0; i < 2; ++i)
            acc[dt][i] = __builtin_amdgcn_mfma_f32_16x16x32_bf16(vf, pf[i], acc[dt][i], 0, 0, 0);
        }
      }
      __builtin_amdgcn_s_setprio(0);
    }
    __syncthreads();
    cur ^= 1;
  }

  #pragma unroll
  for (int i = 0; i < 2; ++i) {
    lsum[i] += __shfl_xor(lsum[i], 16);
    lsum[i] += __shfl_xor(lsum[i], 32);
  }
  float inv0 = 1.f / lsum[0], inv1 = 1.f / lsum[1];
  #pragma unroll
  for (int i = 0; i < 2; ++i) {
    float inv = i ? inv1 : inv0;
    #pragma unroll
    for (int dt = 0; dt < 4; ++dt)
      #pragma unroll
      for (int r2 = 0; r2 < 2; ++r2) {
        unsigned o = (unsigned)f2bf_bits(acc[dt][i][2 * r2] * inv)
                   | ((unsigned)f2bf_bits(acc[dt][i][2 * r2 + 1] * inv) << 16);
        size_t off = (size_t)(q0 + i * 16 + fr) * 2048 + h * 64 + dt * 16 + g * 4 + 2 * r2;
        *reinterpret_cast<unsigned*>(O + off) = o;
      }
  }
}

extern "C" void kernel_launch(void* const* d_in, const int* in_sizes, int n_in,
                              void* d_out, int out_size, void* d_ws, size_t ws_size,
                              hipStream_t stream) {
  const float* x   = (const float*)d_in[0];
  const float* fc  = (const float*)d_in[3];
  const float* fs  = (const float*)d_in[4];
  const float* wq  = (const float*)d_in[5];
  const float* wk  = (const float*)d_in[6];
  const float* wv  = (const float*)d_in[7];
  const float* wo  = (const float*)d_in[8];
  const float* lqR = (const float*)d_in[9];
  const float* lqA = (const float*)d_in[10];
  const float* lqB = (const float*)d_in[11];
  const float* lkR = (const float*)d_in[12];
  const float* lkA = (const float*)d_in[13];
  const float* lkB = (const float*)d_in[14];
  const float* lvR = (const float*)d_in[15];
  const float* lvA = (const float*)d_in[16];
  const float* lvB = (const float*)d_in[17];
  const float* loR = (const float*)d_in[18];
  const float* loA = (const float*)d_in[19];
  const float* loB = (const float*)d_in[20];
  float* out = (float*)d_out;
  char* ws = (char*)d_ws;

  if (ws_size < 58000000u) return;

  bf16* xb   = (bf16*)(ws + 0);            // 8 MB; aliased as AOb after gemm1
  bf16* Wqkv = (bf16*)(ws + 8388608);      // 13.47 MB; aliased as Wout after gemm1
  bf16* Qb   = (bf16*)(ws + 21856256);     // 8 MB
  bf16* Kb   = (bf16*)(ws + 30244864);     // 2 MB
  bf16* Vb   = (bf16*)(ws + 32342016);     // 2 MB
  bf16* Vt   = (bf16*)(ws + 34439168);     // 2 MB
  bf16* C1   = (bf16*)(ws + 36536320);     // 13.47 MB (dead after qkv epilogue)
  bf16* Bt   = (bf16*)(ws + 50003968);     // 640 KB packed LoRA-B (q|k|v|o)
  float* C2  = (float*)(ws + 21856256);    // 17.37 MB, overlays Qb..C1-head (all dead)
  bf16* AOb  = xb;
  bf16* Wout = Wqkv;

  cast4_kernel<<<dim3(S_ * D_ / 4 / 256), dim3(256), 0, stream>>>(x, xb, S_ * D_ / 4);
  pack_qkv_kernel<<<dim3(NQKV_), dim3(256), 0, stream>>>(wq, wk, wv, lqA, lkA, lvA,
                                                         lqR, lkR, lvR, Wqkv);
  pack_bt_kernel<<<dim3(160), dim3(256), 0, stream>>>(lqB, lkB, lvB, loB, Bt);
  gemm_bt_kernel<bf16><<<dim3((NQKV_ + 127) / 128, S_ / 128), dim3(256), 0, stream>>>(
      xb, Wqkv, C1, S_, NQKV_, D_);
  qkv_epilogue3_kernel<<<dim3(12, 32), dim3(256), 0, stream>>>(C1, fc, fs, Bt, Qb, Kb, Vb);
  vt2_kernel<<<dim3(256), dim3(256), 0, stream>>>((const unsigned short*)Vb,
                                                  (unsigned short*)Vt);
  attn_mfma2_kernel<<<dim3(512), dim3(256), 0, stream>>>(Qb, Kb, Vt, AOb);
  pack_out_kernel<<<dim3(NOUT_), dim3(256), 0, stream>>>(wo, loA, loR, Wout);
  gemm_bt_kernel<float><<<dim3((NOUT_ + 127) / 128, S_ / 128), dim3(256), 0, stream>>>(
      AOb, Wout, C2, S_, NOUT_, D_);
  out_epilogue3_kernel<<<dim3(8, 32), dim3(256), 0, stream>>>(C2, Bt, out);
}